// Round 9
// baseline (298.806 us; speedup 1.0000x reference)
//
#include <hip/hip_runtime.h>
#include <hip/hip_bf16.h>
#include <cstdint>
#include <cstddef>

// ---- problem constants ----
#define B_N       4
#define C_INCH    23
#define T_N       8
#define W_IMG     128
#define L_SEQ     8192
#define BLROWS    32768      // B_N * L_SEQ
#define DM_       256
#define D_INNER_  512
#define CONV_DIM_ 544
#define D_PROJ    1064
#define KPATCH    368        // C_INCH*4*4
#define QCH       32         // scan chunk length
#define NCH       256        // chunks per batch

typedef unsigned short ushort_t;
typedef unsigned int uint_t;
typedef __attribute__((ext_vector_type(8))) short short8;
typedef __attribute__((ext_vector_type(4))) float f32x4;

__device__ __forceinline__ float b2f(ushort_t u) {
    union { float f; uint_t u; } v; v.u = ((uint_t)u) << 16; return v.f;
}
__device__ __forceinline__ ushort_t f2b(float f) {
    union { float f; uint_t u; } v; v.f = f;
    uint_t r = v.u + 0x7fffu + ((v.u >> 16) & 1u);
    return (ushort_t)(r >> 16);
}

// async global->LDS, 16B per lane. LDS dest = wave-uniform base + lane*16.
__device__ __forceinline__ void gload_lds16(const ushort_t* g, ushort_t* l) {
    __builtin_amdgcn_global_load_lds(
        (const __attribute__((address_space(1))) unsigned int*)g,
        (__attribute__((address_space(3))) unsigned int*)l, 16, 0, 0);
}

// ---------------------------------------------------------------
// weight prep: dst[Npad][K] bf16 = transpose(src[K][N] fp32) * (rscale?rscale[k]:1)
__global__ void k_transcast(const float* __restrict__ src, ushort_t* __restrict__ dst,
                            int K, int N, const float* __restrict__ rscale) {
    int n = blockIdx.x;
    for (int k = threadIdx.x; k < K; k += 256) {
        float v = 0.f;
        if (n < N) {
            v = src[(size_t)k * N + n];
            if (rscale) v *= rscale[k];
        }
        dst[(size_t)n * K + k] = f2b(v);
    }
}

// patch weights are already [d][k]: direct cast + pad k to 384
__global__ void k_castpad(const float* __restrict__ src, ushort_t* __restrict__ dst) {
    int d = blockIdx.x; int k = threadIdx.x;   // 384 threads
    dst[d * 384 + k] = (k < KPATCH) ? f2b(src[d * KPATCH + k]) : (ushort_t)0;
}

// ---------------------------------------------------------------
// im2col gather: Aim[row][384] bf16, row=(b,t,hp,wp), kk=c*16+i*4+j; kk>=368 -> 0
__global__ void __launch_bounds__(256) k_im2col(const float* __restrict__ x,
                                                ushort_t* __restrict__ Aim) {
    int hp = blockIdx.x, t = blockIdx.y, b = blockIdx.z;
    int tid = threadIdx.x;
    int half = tid >> 7, q = tid & 127;
    int wp = q >> 2, j = q & 3;
    size_t rowbase = (size_t)b * L_SEQ + t * 1024 + hp * 32;
    #pragma unroll
    for (int it = 0; it < 2; ++it) {
        int idx = it * 256 + tid;
        int wpz = idx >> 4, kz = KPATCH + (idx & 15);
        Aim[(rowbase + wpz) * 384 + kz] = 0;
    }
    for (int s2 = 0; s2 < 46; ++s2) {
        int seg = s2 * 2 + half;            // c*4+i
        int c = seg >> 2, i = seg & 3;
        float v = x[(((size_t)(b * C_INCH + c) * T_N + t) << 14) + (size_t)(hp * 4 + i) * W_IMG + q];
        Aim[(rowbase + wp) * 384 + c * 16 + i * 4 + j] = f2b(v);
    }
}

// ---------------------------------------------------------------
// MFMA GEMM: C[M,N] = A[M,K](bf16) @ Wt[n][k](bf16, padded rows) [+bias[n]] [*rowscale[m]].
// 128x128 tile, 4 waves (2x2 of 64x64), BK=64, global_load_lds staging, XOR-swizzled LDS.
template <int K, int N, bool CBF>
__global__ void __launch_bounds__(256) k_mgemm(const ushort_t* __restrict__ A, const int lda,
                                               const ushort_t* __restrict__ Wt,
                                               void* __restrict__ Cv, const int ldc, const int coff,
                                               const float* __restrict__ bias,
                                               const float* __restrict__ rowscale) {
    __shared__ ushort_t Al[128 * 64];
    __shared__ ushort_t Bl[128 * 64];
    const int tid = threadIdx.x;
    const int w = tid >> 6, lane = tid & 63;
    const int wr = w >> 1, wc = w & 1;
    const int rowbase = blockIdx.y * 128;
    const int colbase = blockIdx.x * 128;
    const int g = lane >> 4, r = lane & 15;

    f32x4 acc[4][4];
    #pragma unroll
    for (int i = 0; i < 4; ++i)
        #pragma unroll
        for (int j = 0; j < 4; ++j) acc[i][j] = (f32x4){0.f, 0.f, 0.f, 0.f};

    for (int k0 = 0; k0 < K; k0 += 64) {
        __syncthreads();
        #pragma unroll
        for (int it = 0; it < 4; ++it) {
            int s = it * 256 + (w << 6) + lane;
            int row = s >> 3;
            int c16 = (s & 7) ^ (row & 7);
            gload_lds16(A + (size_t)(rowbase + row) * lda + k0 + c16 * 8,
                        &Al[(size_t)(it * 256 + (w << 6)) * 8]);
        }
        #pragma unroll
        for (int it = 0; it < 4; ++it) {
            int s = it * 256 + (w << 6) + lane;
            int row = s >> 3;
            int c16 = (s & 7) ^ (row & 7);
            gload_lds16(Wt + (size_t)(colbase + row) * K + k0 + c16 * 8,
                        &Bl[(size_t)(it * 256 + (w << 6)) * 8]);
        }
        __syncthreads();

        short8 af[2][4], bf[2][4];
        #pragma unroll
        for (int ks = 0; ks < 2; ++ks)
            #pragma unroll
            for (int mi = 0; mi < 4; ++mi) {
                int row = (wr << 6) + (mi << 4) + r;
                int c16 = ((ks << 2) | g) ^ (row & 7);
                af[ks][mi] = *(const short8*)&Al[(size_t)((row << 3) + c16) * 8];
            }
        #pragma unroll
        for (int ks = 0; ks < 2; ++ks)
            #pragma unroll
            for (int ni = 0; ni < 4; ++ni) {
                int row = (wc << 6) + (ni << 4) + r;
                int c16 = ((ks << 2) | g) ^ (row & 7);
                bf[ks][ni] = *(const short8*)&Bl[(size_t)((row << 3) + c16) * 8];
            }
        #pragma unroll
        for (int ks = 0; ks < 2; ++ks)
            #pragma unroll
            for (int mi = 0; mi < 4; ++mi)
                #pragma unroll
                for (int ni = 0; ni < 4; ++ni)
                    acc[mi][ni] = __builtin_amdgcn_mfma_f32_16x16x32_bf16(
                        af[ks][mi], bf[ks][ni], acc[mi][ni], 0, 0, 0);
    }

    // C store: D col=lane&15, row=(lane>>4)*4+reg
    #pragma unroll
    for (int mi = 0; mi < 4; ++mi) {
        int rw = rowbase + (wr << 6) + (mi << 4) + (g << 2);
        float s0 = 1.f, s1 = 1.f, s2 = 1.f, s3 = 1.f;
        if (rowscale) { s0 = rowscale[rw]; s1 = rowscale[rw+1]; s2 = rowscale[rw+2]; s3 = rowscale[rw+3]; }
        #pragma unroll
        for (int ni = 0; ni < 4; ++ni) {
            int col = colbase + (wc << 6) + (ni << 4) + r;
            if (col < N) {
                float bv = bias ? bias[col] : 0.f;
                f32x4 v = acc[mi][ni];
                float vr[4] = {v[0]*s0 + bv, v[1]*s1 + bv, v[2]*s2 + bv, v[3]*s3 + bv};
                #pragma unroll
                for (int j = 0; j < 4; ++j) {
                    size_t cidx = (size_t)(rw + j) * ldc + coff + col;
                    if (CBF) ((ushort_t*)Cv)[cidx] = f2b(vr[j]);
                    else     ((float*)Cv)[cidx]   = vr[j];
                }
            }
        }
    }
}

// ---------------------------------------------------------------
// causal depthwise conv (kernel 4) + silu, sliding-window over 8 rows/block.
__global__ void __launch_bounds__(256) k_conv(const ushort_t* __restrict__ xbcdt,
                                              const float* __restrict__ cw,
                                              const float* __restrict__ cb,
                                              const float* __restrict__ dtb,
                                              const float* __restrict__ alog,
                                              ushort_t* __restrict__ xbc,
                                              float* __restrict__ bc32,
                                              float* __restrict__ dtv,
                                              float* __restrict__ dAv) {
    int tid = threadIdx.x;
    int rb = blockIdx.x * 8;            // first row of this block
    int srb = rb & (L_SEQ - 1);         // seq pos within batch
    #pragma unroll
    for (int it = 0; it < 3; ++it) {
        int ch = it * 256 + tid;
        if (ch >= 552) break;
        if (ch < CONV_DIM_) {
            float w0 = cw[ch * 4 + 0], w1 = cw[ch * 4 + 1];
            float w2 = cw[ch * 4 + 2], w3 = cw[ch * 4 + 3];
            float bias = cb[ch];
            float win[11];
            #pragma unroll
            for (int j = 0; j < 11; ++j) {
                int sj = srb + j - 3;
                win[j] = (sj >= 0) ? b2f(xbcdt[(size_t)(rb + j - 3) * 640 + ch]) : 0.f;
            }
            #pragma unroll
            for (int r = 0; r < 8; ++r) {
                float acc = bias + win[r] * w0 + win[r + 1] * w1 + win[r + 2] * w2 + win[r + 3] * w3;
                float s = acc / (1.f + __expf(-acc));
                size_t row = rb + r;
                if (ch < 512) xbc[row * 512 + ch] = f2b(s);
                else          bc32[row * 32 + (ch - 512)] = s;
            }
        } else {
            int h = ch - CONV_DIM_;
            float A = -__expf(alog[h]);
            float db = dtb[h];
            #pragma unroll
            for (int r = 0; r < 8; ++r) {
                size_t row = rb + r;
                float v = b2f(xbcdt[row * 640 + ch]) + db;
                float sp = (v > 20.f) ? v : log1pf(__expf(v));
                dtv[row * 8 + h] = sp;
                dAv[row * 8 + h] = __expf(sp * A);
            }
        }
    }
}

// ---------------------------------------------------------------
// scan phase 1: chunk-final local states ONLY (from zero state) + per-chunk decay.
// block = 4 heads x 64 p; grid (NCH, 2, B).
__global__ void __launch_bounds__(256) k_scan1(const ushort_t* __restrict__ xbc,
                                               const float* __restrict__ bc32,
                                               const float* __restrict__ dtv,
                                               const float* __restrict__ dAv,
                                               float* __restrict__ sbuf,
                                               float* __restrict__ cdf) {
    int c = blockIdx.x, b = blockIdx.z;
    int tid = threadIdx.x;
    int h = blockIdx.y * 4 + (tid >> 6);
    int p = tid & 63;
    float st[16];
    #pragma unroll
    for (int n = 0; n < 16; ++n) st[n] = 0.f;
    float cd = 1.f;
    size_t row0 = (size_t)b * L_SEQ + (size_t)c * QCH;
    for (int s = 0; s < QCH; ++s) {
        size_t row = row0 + s;
        float da  = dAv[row * 8 + h];
        float dtt = dtv[row * 8 + h];
        float xh  = b2f(xbc[row * 512 + h * 64 + p]);
        const float4* B4 = (const float4*)(bc32 + row * 32);
        float xdt = xh * dtt;
        #pragma unroll
        for (int q = 0; q < 4; ++q) {
            float4 Bv = B4[q];
            st[q*4+0] = da * st[q*4+0] + xdt * Bv.x;
            st[q*4+1] = da * st[q*4+1] + xdt * Bv.y;
            st[q*4+2] = da * st[q*4+2] + xdt * Bv.z;
            st[q*4+3] = da * st[q*4+3] + xdt * Bv.w;
        }
        cd *= da;
    }
    size_t base = (size_t)((b * 8 + h) * NCH + c) * 1024 + p * 16;
    #pragma unroll
    for (int q = 0; q < 4; ++q)
        *(float4*)&sbuf[base + q * 4] = make_float4(st[q*4], st[q*4+1], st[q*4+2], st[q*4+3]);
    if (p == 0) cdf[(b * 8 + h) * NCH + c] = cd;
}

// ---------------------------------------------------------------
// phase 2: sequential chain over chunks (tiny). block = (h, b); thread holds 4 states.
__global__ void __launch_bounds__(256) k_chain(const float* __restrict__ sbuf,
                                               const float* __restrict__ cdf,
                                               float* __restrict__ hin) {
    int h = blockIdx.x, b = blockIdx.y;
    int tid = threadIdx.x;
    float4 H = make_float4(0.f, 0.f, 0.f, 0.f);
    size_t base = (size_t)((b * 8 + h) * NCH) * 1024;
    for (int c = 0; c < NCH; ++c) {
        *(float4*)&hin[base + (size_t)c * 1024 + tid * 4] = H;
        float cdfv = cdf[(b * 8 + h) * NCH + c];
        float4 S = *(const float4*)&sbuf[base + (size_t)c * 1024 + tid * 4];
        H.x = cdfv * H.x + S.x;
        H.y = cdfv * H.y + S.y;
        H.z = cdfv * H.z + S.z;
        H.w = cdfv * H.w + S.w;
    }
}

// ---------------------------------------------------------------
// scan phase 3: full re-scan from Hin (exact y) + gate; yg -> SEPARATE buffer
// (no aliasing -> cross-step prefetch). Manual 1-step software pipeline;
// one-row overread on the final step lands in adjacent workspace (safe).
// block = 8 heads x 64 p; grid (NCH, B).
__global__ void __launch_bounds__(512) k_scan2(const ushort_t* __restrict__ xbc,
                                               const ushort_t* __restrict__ z_bf,
                                               const float* __restrict__ bc32,
                                               const float* __restrict__ dtv,
                                               const float* __restrict__ dAv,
                                               const float* __restrict__ Dp,
                                               const float* __restrict__ hin,
                                               ushort_t* __restrict__ yg_out) {
    int c = blockIdx.x, b = blockIdx.y;
    int tid = threadIdx.x;
    int h = tid >> 6, p = tid & 63;
    int off = h * 64 + p;
    float st[16];
    const float4* H = (const float4*)&hin[(size_t)((b * 8 + h) * NCH + c) * 1024 + p * 16];
    #pragma unroll
    for (int q = 0; q < 4; ++q) {
        float4 Hv = H[q];
        st[q*4+0] = Hv.x; st[q*4+1] = Hv.y; st[q*4+2] = Hv.z; st[q*4+3] = Hv.w;
    }
    float Dh = Dp[h];
    size_t row = (size_t)b * L_SEQ + (size_t)c * QCH;

    // prologue loads (step 0)
    float da  = dAv[row * 8 + h];
    float dtt = dtv[row * 8 + h];
    float xh  = b2f(xbc[row * 512 + off]);
    float zz  = b2f(z_bf[row * 512 + off]);
    float4 Bc[4], Cc[4];
    {
        const float4* B4 = (const float4*)(bc32 + row * 32);
        #pragma unroll
        for (int q = 0; q < 4; ++q) { Bc[q] = B4[q]; Cc[q] = B4[q + 4]; }
    }

    for (int s = 0; s < QCH; ++s) {
        // issue next-step loads (overread on last iter stays in d_ws: safe)
        size_t rn = row + 1;
        float da_n  = dAv[rn * 8 + h];
        float dt_n  = dtv[rn * 8 + h];
        float xh_n  = b2f(xbc[rn * 512 + off]);
        float zz_n  = b2f(z_bf[rn * 512 + off]);
        float4 Bn[4], Cn[4];
        const float4* B4n = (const float4*)(bc32 + rn * 32);
        #pragma unroll
        for (int q = 0; q < 4; ++q) { Bn[q] = B4n[q]; Cn[q] = B4n[q + 4]; }

        // compute current step
        float xdt = xh * dtt;
        float d0 = 0.f, d1 = 0.f, d2 = 0.f, d3 = 0.f;
        #pragma unroll
        for (int q = 0; q < 4; ++q) {
            st[q*4+0] = da * st[q*4+0] + xdt * Bc[q].x;
            st[q*4+1] = da * st[q*4+1] + xdt * Bc[q].y;
            st[q*4+2] = da * st[q*4+2] + xdt * Bc[q].z;
            st[q*4+3] = da * st[q*4+3] + xdt * Bc[q].w;
            d0 += st[q*4+0] * Cc[q].x;
            d1 += st[q*4+1] * Cc[q].y;
            d2 += st[q*4+2] * Cc[q].z;
            d3 += st[q*4+3] * Cc[q].w;
        }
        float y = (d0 + d1) + (d2 + d3) + Dh * xh;
        float yg = y * (zz / (1.f + __expf(-zz)));
        yg_out[row * 512 + off] = f2b(yg);

        // rotate pipeline
        row = rn; da = da_n; dtt = dt_n; xh = xh_n; zz = zz_n;
        #pragma unroll
        for (int q = 0; q < 4; ++q) { Bc[q] = Bn[q]; Cc[q] = Cn[q]; }
    }
}

// ---------------------------------------------------------------
// row scale from yg: scale[row] = rsqrt(mean(yg^2) + eps). one wave per row.
__global__ void __launch_bounds__(256) k_rsum(const ushort_t* __restrict__ yg,
                                              float* __restrict__ scale) {
    int wid = threadIdx.x >> 6, lane = threadIdx.x & 63;
    int row = blockIdx.x * 4 + wid;
    short8 v = *(const short8*)&yg[(size_t)row * 512 + lane * 8];
    float s = 0.f;
    #pragma unroll
    for (int j = 0; j < 8; ++j) {
        float f = b2f((ushort_t)v[j]);
        s += f * f;
    }
    #pragma unroll
    for (int off = 32; off >= 1; off >>= 1) s += __shfl_xor(s, off);
    if (lane == 0) scale[row] = rsqrtf(s * (1.f / 512.f) + 1e-5f);
}

// ---------------------------------------------------------------
__global__ void __launch_bounds__(256) k_scatter(const ushort_t* __restrict__ tmp,
                                                 const float* __restrict__ ub,
                                                 const float* __restrict__ xin,
                                                 float* __restrict__ out) {
    int tid = threadIdx.x;
    int w = tid & 127;
    int h = (blockIdx.x << 1) | (tid >> 7);
    int c = blockIdx.y >> 3, t = blockIdx.y & 7;
    int b = blockIdx.z;
    size_t row = (size_t)b * L_SEQ + t * 1024 + (h >> 2) * 32 + (w >> 2);
    int kk = c * 16 + (h & 3) * 4 + (w & 3);
    size_t oidx = (((size_t)(b * C_INCH + c) * T_N + t) << 14) + (size_t)h * W_IMG + w;
    out[oidx] = b2f(tmp[row * KPATCH + kk]) + ub[c] + xin[oidx];
}

// ---------------------------------------------------------------
extern "C" void kernel_launch(void* const* d_in, const int* in_sizes, int n_in,
                              void* d_out, int out_size, void* d_ws, size_t ws_size,
                              hipStream_t stream) {
    const float* x       = (const float*)d_in[0];
    const float* patch_w = (const float*)d_in[1];
    const float* patch_b = (const float*)d_in[2];
    const float* W_in    = (const float*)d_in[3];
    const float* conv_w  = (const float*)d_in[4];
    const float* conv_b  = (const float*)d_in[5];
    const float* dt_bias = (const float*)d_in[6];
    const float* A_log   = (const float*)d_in[7];
    const float* D_param = (const float*)d_in[8];
    const float* norm_w  = (const float*)d_in[9];
    const float* W_out   = (const float*)d_in[10];
    const float* unemb_w = (const float*)d_in[11];
    const float* unemb_b = (const float*)d_in[12];
    float* out = (float*)d_out;

    // ---- workspace carve ----
    // region1 (33.5 MB) serves, in strictly disjoint lifetimes:
    //   Aim  (bf16, 25 MB): im2col -> patch GEMM
    //   sbuf (f32, 33.5 MB): scan1 -> chain
    //   tmp  (bf16, 25 MB): unembed GEMM -> scatter
    char* p = (char*)d_ws;
    float* region1 = (float*)p; p += (size_t)32 * NCH * 1024 * 4;      // 33.5 MB
    float* dtv  = (float*)p;   p += (size_t)BLROWS * 8 * 4;
    float* dAv  = (float*)p;   p += (size_t)BLROWS * 8 * 4;
    float* scale= (float*)p;   p += (size_t)BLROWS * 4;
    float* cdf  = (float*)p;   p += (size_t)32 * NCH * 4;
    float* hin  = (float*)p;   p += (size_t)32 * NCH * 1024 * 4;       // 33.5 MB
    float* bc32 = (float*)p;   p += (size_t)BLROWS * 32 * 4;           // 4.2 MB
    ushort_t* Wt_p   = (ushort_t*)p; p += (size_t)256 * 384 * 2;
    ushort_t* Wt_in  = (ushort_t*)p; p += (size_t)1152 * 256 * 2;
    ushort_t* Wt_out = (ushort_t*)p; p += (size_t)256 * 512 * 2;
    ushort_t* Wt_un  = (ushort_t*)p; p += (size_t)384 * 256 * 2;
    ushort_t* xs     = (ushort_t*)p; p += (size_t)BLROWS * DM_ * 2;    // 16.8 MB
    ushort_t* xbc    = (ushort_t*)p; p += (size_t)BLROWS * 512 * 2;    // 33.5 MB
    ushort_t* z_bf   = (ushort_t*)p; p += (size_t)BLROWS * 512 * 2;    // 33.5 MB
    ushort_t* xbcdt  = (ushort_t*)p; p += (size_t)BLROWS * 640 * 2;    // 41.9 MB (later: yg)
    size_t need = (size_t)(p - (char*)d_ws);
    if (ws_size < need) return;

    ushort_t* Aim  = (ushort_t*)region1;
    float*    sbuf = region1;
    ushort_t* tmp  = (ushort_t*)region1;
    ushort_t* yg   = xbcdt;             // yg overlays xbcdt (dead after conv)

    k_castpad<<<256, 384, 0, stream>>>(patch_w, Wt_p);
    k_transcast<<<1152, 256, 0, stream>>>(W_in, Wt_in, 256, 1064, nullptr);
    k_transcast<<<256, 256, 0, stream>>>(W_out, Wt_out, 512, 256, norm_w);  // fold RMSNorm weight
    k_transcast<<<384, 256, 0, stream>>>(unemb_w, Wt_un, 256, 368, nullptr);

    k_im2col<<<dim3(32, 8, 4), 256, 0, stream>>>(x, Aim);
    k_mgemm<384, 256, true><<<dim3(2, 256), 256, 0, stream>>>(Aim, 384, Wt_p, xs, 256, 0, patch_b, nullptr);

    // in-proj split: z cols 0..511 -> z_bf; xBC+dt cols 512..1063 -> xbcdt
    k_mgemm<256, 512, true><<<dim3(4, 256), 256, 0, stream>>>(xs, 256, Wt_in, z_bf, 512, 0, nullptr, nullptr);
    k_mgemm<256, 552, true><<<dim3(5, 256), 256, 0, stream>>>(xs, 256, Wt_in + (size_t)512 * 256, xbcdt, 640, 0, nullptr, nullptr);

    k_conv<<<BLROWS / 8, 256, 0, stream>>>(xbcdt, conv_w, conv_b, dt_bias, A_log, xbc, bc32, dtv, dAv);

    k_scan1<<<dim3(NCH, 2, 4), 256, 0, stream>>>(xbc, bc32, dtv, dAv, sbuf, cdf);
    k_chain<<<dim3(8, 4), 256, 0, stream>>>(sbuf, cdf, hin);
    k_scan2<<<dim3(NCH, 4), 512, 0, stream>>>(xbc, z_bf, bc32, dtv, dAv, D_param, hin, yg);
    k_rsum<<<BLROWS / 4, 256, 0, stream>>>(yg, scale);

    // out-proj with fused RMSNorm row-scale: out_seq bf16 -> xs
    k_mgemm<512, 256, true><<<dim3(2, 256), 256, 0, stream>>>(yg, 512, Wt_out, xs, DM_, 0, nullptr, scale);

    k_mgemm<256, 368, true><<<dim3(3, 256), 256, 0, stream>>>(xs, 256, Wt_un, tmp, KPATCH, 0, nullptr, nullptr);

    k_scatter<<<dim3(64, 184, 4), 256, 0, stream>>>(tmp, unemb_b, x, out);
}

// Round 10
// 290.387 us; speedup vs baseline: 1.0290x; 1.0290x over previous
//
#include <hip/hip_runtime.h>
#include <hip/hip_bf16.h>
#include <cstdint>
#include <cstddef>

// ---- problem constants ----
#define B_N       4
#define C_INCH    23
#define T_N       8
#define W_IMG     128
#define L_SEQ     8192
#define BLROWS    32768      // B_N * L_SEQ
#define DM_       256
#define D_INNER_  512
#define CONV_DIM_ 544
#define D_PROJ    1064
#define KPATCH    368        // C_INCH*4*4
#define QCH       64         // scan chunk length
#define NCH       128        // chunks per batch
#define RECW      48         // packed scan record width (floats): B16 C16 dA8 dt8

typedef unsigned short ushort_t;
typedef unsigned int uint_t;
typedef __attribute__((ext_vector_type(8))) short short8;
typedef __attribute__((ext_vector_type(4))) float f32x4;

__device__ __forceinline__ float b2f(ushort_t u) {
    union { float f; uint_t u; } v; v.u = ((uint_t)u) << 16; return v.f;
}
__device__ __forceinline__ ushort_t f2b(float f) {
    union { float f; uint_t u; } v; v.f = f;
    uint_t r = v.u + 0x7fffu + ((v.u >> 16) & 1u);
    return (ushort_t)(r >> 16);
}

// async global->LDS, 16B per lane. LDS dest = wave-uniform base + lane*16.
__device__ __forceinline__ void gload_lds16(const ushort_t* g, ushort_t* l) {
    __builtin_amdgcn_global_load_lds(
        (const __attribute__((address_space(1))) unsigned int*)g,
        (__attribute__((address_space(3))) unsigned int*)l, 16, 0, 0);
}

// ---------------------------------------------------------------
// weight prep: dst[Npad][K] bf16 = transpose(src[K][N] fp32) * (rscale?rscale[k]:1)
__global__ void k_transcast(const float* __restrict__ src, ushort_t* __restrict__ dst,
                            int K, int N, const float* __restrict__ rscale) {
    int n = blockIdx.x;
    for (int k = threadIdx.x; k < K; k += 256) {
        float v = 0.f;
        if (n < N) {
            v = src[(size_t)k * N + n];
            if (rscale) v *= rscale[k];
        }
        dst[(size_t)n * K + k] = f2b(v);
    }
}

// patch weights are already [d][k]: direct cast + pad k to 384
__global__ void k_castpad(const float* __restrict__ src, ushort_t* __restrict__ dst) {
    int d = blockIdx.x; int k = threadIdx.x;   // 384 threads
    dst[d * 384 + k] = (k < KPATCH) ? f2b(src[d * KPATCH + k]) : (ushort_t)0;
}

// ---------------------------------------------------------------
// im2col gather: Aim[row][384] bf16, row=(b,t,hp,wp), kk=c*16+i*4+j; kk>=368 -> 0
__global__ void __launch_bounds__(256) k_im2col(const float* __restrict__ x,
                                                ushort_t* __restrict__ Aim) {
    int hp = blockIdx.x, t = blockIdx.y, b = blockIdx.z;
    int tid = threadIdx.x;
    int half = tid >> 7, q = tid & 127;
    int wp = q >> 2, j = q & 3;
    size_t rowbase = (size_t)b * L_SEQ + t * 1024 + hp * 32;
    #pragma unroll
    for (int it = 0; it < 2; ++it) {
        int idx = it * 256 + tid;
        int wpz = idx >> 4, kz = KPATCH + (idx & 15);
        Aim[(rowbase + wpz) * 384 + kz] = 0;
    }
    for (int s2 = 0; s2 < 46; ++s2) {
        int seg = s2 * 2 + half;            // c*4+i
        int c = seg >> 2, i = seg & 3;
        float v = x[(((size_t)(b * C_INCH + c) * T_N + t) << 14) + (size_t)(hp * 4 + i) * W_IMG + q];
        Aim[(rowbase + wp) * 384 + c * 16 + i * 4 + j] = f2b(v);
    }
}

// ---------------------------------------------------------------
// MFMA GEMM: C[M,N] = A[M,K](bf16) @ Wt[n][k](bf16, padded rows) [+bias[n]] [*rowscale[m]].
// 128x128 tile, 4 waves (2x2 of 64x64), BK=64, global_load_lds staging, XOR-swizzled LDS.
template <int K, int N, bool CBF>
__global__ void __launch_bounds__(256) k_mgemm(const ushort_t* __restrict__ A, const int lda,
                                               const ushort_t* __restrict__ Wt,
                                               void* __restrict__ Cv, const int ldc, const int coff,
                                               const float* __restrict__ bias,
                                               const float* __restrict__ rowscale) {
    __shared__ ushort_t Al[128 * 64];
    __shared__ ushort_t Bl[128 * 64];
    const int tid = threadIdx.x;
    const int w = tid >> 6, lane = tid & 63;
    const int wr = w >> 1, wc = w & 1;
    const int rowbase = blockIdx.y * 128;
    const int colbase = blockIdx.x * 128;
    const int g = lane >> 4, r = lane & 15;

    f32x4 acc[4][4];
    #pragma unroll
    for (int i = 0; i < 4; ++i)
        #pragma unroll
        for (int j = 0; j < 4; ++j) acc[i][j] = (f32x4){0.f, 0.f, 0.f, 0.f};

    for (int k0 = 0; k0 < K; k0 += 64) {
        __syncthreads();
        #pragma unroll
        for (int it = 0; it < 4; ++it) {
            int s = it * 256 + (w << 6) + lane;
            int row = s >> 3;
            int c16 = (s & 7) ^ (row & 7);
            gload_lds16(A + (size_t)(rowbase + row) * lda + k0 + c16 * 8,
                        &Al[(size_t)(it * 256 + (w << 6)) * 8]);
        }
        #pragma unroll
        for (int it = 0; it < 4; ++it) {
            int s = it * 256 + (w << 6) + lane;
            int row = s >> 3;
            int c16 = (s & 7) ^ (row & 7);
            gload_lds16(Wt + (size_t)(colbase + row) * K + k0 + c16 * 8,
                        &Bl[(size_t)(it * 256 + (w << 6)) * 8]);
        }
        __syncthreads();

        short8 af[2][4], bf[2][4];
        #pragma unroll
        for (int ks = 0; ks < 2; ++ks)
            #pragma unroll
            for (int mi = 0; mi < 4; ++mi) {
                int row = (wr << 6) + (mi << 4) + r;
                int c16 = ((ks << 2) | g) ^ (row & 7);
                af[ks][mi] = *(const short8*)&Al[(size_t)((row << 3) + c16) * 8];
            }
        #pragma unroll
        for (int ks = 0; ks < 2; ++ks)
            #pragma unroll
            for (int ni = 0; ni < 4; ++ni) {
                int row = (wc << 6) + (ni << 4) + r;
                int c16 = ((ks << 2) | g) ^ (row & 7);
                bf[ks][ni] = *(const short8*)&Bl[(size_t)((row << 3) + c16) * 8];
            }
        #pragma unroll
        for (int ks = 0; ks < 2; ++ks)
            #pragma unroll
            for (int mi = 0; mi < 4; ++mi)
                #pragma unroll
                for (int ni = 0; ni < 4; ++ni)
                    acc[mi][ni] = __builtin_amdgcn_mfma_f32_16x16x32_bf16(
                        af[ks][mi], bf[ks][ni], acc[mi][ni], 0, 0, 0);
    }

    // C store: D col=lane&15, row=(lane>>4)*4+reg
    #pragma unroll
    for (int mi = 0; mi < 4; ++mi) {
        int rw = rowbase + (wr << 6) + (mi << 4) + (g << 2);
        float s0 = 1.f, s1 = 1.f, s2 = 1.f, s3 = 1.f;
        if (rowscale) { s0 = rowscale[rw]; s1 = rowscale[rw+1]; s2 = rowscale[rw+2]; s3 = rowscale[rw+3]; }
        #pragma unroll
        for (int ni = 0; ni < 4; ++ni) {
            int col = colbase + (wc << 6) + (ni << 4) + r;
            if (col < N) {
                float bv = bias ? bias[col] : 0.f;
                f32x4 v = acc[mi][ni];
                float vr[4] = {v[0]*s0 + bv, v[1]*s1 + bv, v[2]*s2 + bv, v[3]*s3 + bv};
                #pragma unroll
                for (int j = 0; j < 4; ++j) {
                    size_t cidx = (size_t)(rw + j) * ldc + coff + col;
                    if (CBF) ((ushort_t*)Cv)[cidx] = f2b(vr[j]);
                    else     ((float*)Cv)[cidx]   = vr[j];
                }
            }
        }
    }
}

// ---------------------------------------------------------------
// causal depthwise conv (kernel 4) + silu, sliding-window over 8 rows/block.
// ch<512 -> xbc bf16; 512..543 (B,C) -> brec[row][0..31]; dt -> brec[row][32+h]=dA, [40+h]=dt.
__global__ void __launch_bounds__(256) k_conv(const ushort_t* __restrict__ xbcdt,
                                              const float* __restrict__ cw,
                                              const float* __restrict__ cb,
                                              const float* __restrict__ dtb,
                                              const float* __restrict__ alog,
                                              ushort_t* __restrict__ xbc,
                                              float* __restrict__ brec,
                                              float* __restrict__ dtv,   // unused
                                              float* __restrict__ dAv) { // unused
    int tid = threadIdx.x;
    int rb = blockIdx.x * 8;            // first row of this block
    int srb = rb & (L_SEQ - 1);         // seq pos within batch
    #pragma unroll
    for (int it = 0; it < 3; ++it) {
        int ch = it * 256 + tid;
        if (ch >= 552) break;
        if (ch < CONV_DIM_) {
            float w0 = cw[ch * 4 + 0], w1 = cw[ch * 4 + 1];
            float w2 = cw[ch * 4 + 2], w3 = cw[ch * 4 + 3];
            float bias = cb[ch];
            float win[11];
            #pragma unroll
            for (int j = 0; j < 11; ++j) {
                int sj = srb + j - 3;
                win[j] = (sj >= 0) ? b2f(xbcdt[(size_t)(rb + j - 3) * 640 + ch]) : 0.f;
            }
            #pragma unroll
            for (int r = 0; r < 8; ++r) {
                float acc = bias + win[r] * w0 + win[r + 1] * w1 + win[r + 2] * w2 + win[r + 3] * w3;
                float s = acc / (1.f + __expf(-acc));
                size_t row = rb + r;
                if (ch < 512) xbc[row * 512 + ch] = f2b(s);
                else          brec[row * RECW + (ch - 512)] = s;
            }
        } else {
            int h = ch - CONV_DIM_;
            float A = -__expf(alog[h]);
            float db = dtb[h];
            #pragma unroll
            for (int r = 0; r < 8; ++r) {
                size_t row = rb + r;
                float v = b2f(xbcdt[row * 640 + ch]) + db;
                float sp = (v > 20.f) ? v : log1pf(__expf(v));
                brec[row * RECW + 32 + h] = __expf(sp * A);   // dA
                brec[row * RECW + 40 + h] = sp;               // dt
            }
        }
    }
}

// ---------------------------------------------------------------
// scan phase 1: chunk-final local states ONLY + per-chunk decay.
// Records staged in LDS once. block = 4 heads x 64 p; grid (NCH, 2, B).
__global__ void __launch_bounds__(256) k_scan1(const ushort_t* __restrict__ xbc,
                                               const float* __restrict__ brec,
                                               float* __restrict__ sbuf,
                                               float* __restrict__ cdf) {
    __shared__ float rec[QCH * RECW];     // 12 KB
    int c = blockIdx.x, b = blockIdx.z;
    int tid = threadIdx.x;
    int h = blockIdx.y * 4 + (tid >> 6);
    int p = tid & 63;
    size_t row0 = (size_t)b * L_SEQ + (size_t)c * QCH;

    // stage chunk records: QCH*RECW/4 = 768 float4
    {
        const float4* src = (const float4*)(brec + row0 * RECW);
        float4* dst = (float4*)rec;
        #pragma unroll
        for (int i = 0; i < 3; ++i) dst[i * 256 + tid] = src[i * 256 + tid];
    }
    __syncthreads();

    float st[16];
    #pragma unroll
    for (int n = 0; n < 16; ++n) st[n] = 0.f;
    float cd = 1.f;
    // prologue xh prefetch
    float xh = b2f(xbc[row0 * 512 + h * 64 + p]);
    for (int s = 0; s < QCH; ++s) {
        float xh_n = b2f(xbc[(row0 + s + 1) * 512 + h * 64 + p]);  // overread on last iter is safe
        const float* r = rec + s * RECW;
        float da  = r[32 + h];
        float dtt = r[40 + h];
        float xdt = xh * dtt;
        const float4* B4 = (const float4*)r;
        #pragma unroll
        for (int q = 0; q < 4; ++q) {
            float4 Bv = B4[q];
            st[q*4+0] = da * st[q*4+0] + xdt * Bv.x;
            st[q*4+1] = da * st[q*4+1] + xdt * Bv.y;
            st[q*4+2] = da * st[q*4+2] + xdt * Bv.z;
            st[q*4+3] = da * st[q*4+3] + xdt * Bv.w;
        }
        cd *= da;
        xh = xh_n;
    }
    size_t base = (size_t)((b * 8 + h) * NCH + c) * 1024 + p * 16;
    #pragma unroll
    for (int q = 0; q < 4; ++q)
        *(float4*)&sbuf[base + q * 4] = make_float4(st[q*4], st[q*4+1], st[q*4+2], st[q*4+3]);
    if (p == 0) cdf[(b * 8 + h) * NCH + c] = cd;
}

// ---------------------------------------------------------------
// phase 2: sequential chain over chunks (tiny). block = (h, b); thread holds 4 states.
__global__ void __launch_bounds__(256) k_chain(const float* __restrict__ sbuf,
                                               const float* __restrict__ cdf,
                                               float* __restrict__ hin) {
    int h = blockIdx.x, b = blockIdx.y;
    int tid = threadIdx.x;
    float4 H = make_float4(0.f, 0.f, 0.f, 0.f);
    size_t base = (size_t)((b * 8 + h) * NCH) * 1024;
    for (int c = 0; c < NCH; ++c) {
        *(float4*)&hin[base + (size_t)c * 1024 + tid * 4] = H;
        float cdfv = cdf[(b * 8 + h) * NCH + c];
        float4 S = *(const float4*)&sbuf[base + (size_t)c * 1024 + tid * 4];
        H.x = cdfv * H.x + S.x;
        H.y = cdfv * H.y + S.y;
        H.z = cdfv * H.z + S.z;
        H.w = cdfv * H.w + S.w;
    }
}

// ---------------------------------------------------------------
// scan phase 3: full re-scan from Hin (exact y) + gate -> yg buffer.
// Records staged in LDS once; xh/zz keep 1-step prefetch.
// block = 8 heads x 64 p; grid (NCH, B).
__global__ void __launch_bounds__(512) k_scan2(const ushort_t* __restrict__ xbc,
                                               const ushort_t* __restrict__ z_bf,
                                               const float* __restrict__ brec,
                                               const float* __restrict__ Dp,
                                               const float* __restrict__ hin,
                                               ushort_t* __restrict__ yg_out) {
    __shared__ float rec[QCH * RECW];     // 12 KB
    int c = blockIdx.x, b = blockIdx.y;
    int tid = threadIdx.x;
    int h = tid >> 6, p = tid & 63;
    int off = h * 64 + p;
    size_t row0 = (size_t)b * L_SEQ + (size_t)c * QCH;

    // stage chunk records: 768 float4, 512 threads
    {
        const float4* src = (const float4*)(brec + row0 * RECW);
        float4* dst = (float4*)rec;
        dst[tid] = src[tid];
        if (tid < 256) dst[512 + tid] = src[512 + tid];
    }

    float st[16];
    const float4* H = (const float4*)&hin[(size_t)((b * 8 + h) * NCH + c) * 1024 + p * 16];
    #pragma unroll
    for (int q = 0; q < 4; ++q) {
        float4 Hv = H[q];
        st[q*4+0] = Hv.x; st[q*4+1] = Hv.y; st[q*4+2] = Hv.z; st[q*4+3] = Hv.w;
    }
    float Dh = Dp[h];
    // prologue xh/zz prefetch
    float xh = b2f(xbc[row0 * 512 + off]);
    float zz = b2f(z_bf[row0 * 512 + off]);
    __syncthreads();

    size_t row = row0;
    for (int s = 0; s < QCH; ++s) {
        size_t rn = row + 1;
        float xh_n = b2f(xbc[rn * 512 + off]);   // overread on last iter stays in d_ws: safe
        float zz_n = b2f(z_bf[rn * 512 + off]);

        const float* r = rec + s * RECW;
        float da  = r[32 + h];
        float dtt = r[40 + h];
        float xdt = xh * dtt;
        const float4* B4 = (const float4*)r;
        const float4* C4 = (const float4*)(r + 16);
        float d0 = 0.f, d1 = 0.f, d2 = 0.f, d3 = 0.f;
        #pragma unroll
        for (int q = 0; q < 4; ++q) {
            float4 Bv = B4[q];
            float4 Cv = C4[q];
            st[q*4+0] = da * st[q*4+0] + xdt * Bv.x;
            st[q*4+1] = da * st[q*4+1] + xdt * Bv.y;
            st[q*4+2] = da * st[q*4+2] + xdt * Bv.z;
            st[q*4+3] = da * st[q*4+3] + xdt * Bv.w;
            d0 += st[q*4+0] * Cv.x;
            d1 += st[q*4+1] * Cv.y;
            d2 += st[q*4+2] * Cv.z;
            d3 += st[q*4+3] * Cv.w;
        }
        float y = (d0 + d1) + (d2 + d3) + Dh * xh;
        float yg = y * (zz / (1.f + __expf(-zz)));
        yg_out[row * 512 + off] = f2b(yg);

        row = rn; xh = xh_n; zz = zz_n;
    }
}

// ---------------------------------------------------------------
// row scale from yg: scale[row] = rsqrt(mean(yg^2) + eps). one wave per row.
__global__ void __launch_bounds__(256) k_rsum(const ushort_t* __restrict__ yg,
                                              float* __restrict__ scale) {
    int wid = threadIdx.x >> 6, lane = threadIdx.x & 63;
    int row = blockIdx.x * 4 + wid;
    short8 v = *(const short8*)&yg[(size_t)row * 512 + lane * 8];
    float s = 0.f;
    #pragma unroll
    for (int j = 0; j < 8; ++j) {
        float f = b2f((ushort_t)v[j]);
        s += f * f;
    }
    #pragma unroll
    for (int off = 32; off >= 1; off >>= 1) s += __shfl_xor(s, off);
    if (lane == 0) scale[row] = rsqrtf(s * (1.f / 512.f) + 1e-5f);
}

// ---------------------------------------------------------------
__global__ void __launch_bounds__(256) k_scatter(const ushort_t* __restrict__ tmp,
                                                 const float* __restrict__ ub,
                                                 const float* __restrict__ xin,
                                                 float* __restrict__ out) {
    int tid = threadIdx.x;
    int w = tid & 127;
    int h = (blockIdx.x << 1) | (tid >> 7);
    int c = blockIdx.y >> 3, t = blockIdx.y & 7;
    int b = blockIdx.z;
    size_t row = (size_t)b * L_SEQ + t * 1024 + (h >> 2) * 32 + (w >> 2);
    int kk = c * 16 + (h & 3) * 4 + (w & 3);
    size_t oidx = (((size_t)(b * C_INCH + c) * T_N + t) << 14) + (size_t)h * W_IMG + w;
    out[oidx] = b2f(tmp[row * KPATCH + kk]) + ub[c] + xin[oidx];
}

// ---------------------------------------------------------------
extern "C" void kernel_launch(void* const* d_in, const int* in_sizes, int n_in,
                              void* d_out, int out_size, void* d_ws, size_t ws_size,
                              hipStream_t stream) {
    const float* x       = (const float*)d_in[0];
    const float* patch_w = (const float*)d_in[1];
    const float* patch_b = (const float*)d_in[2];
    const float* W_in    = (const float*)d_in[3];
    const float* conv_w  = (const float*)d_in[4];
    const float* conv_b  = (const float*)d_in[5];
    const float* dt_bias = (const float*)d_in[6];
    const float* A_log   = (const float*)d_in[7];
    const float* D_param = (const float*)d_in[8];
    const float* norm_w  = (const float*)d_in[9];
    const float* W_out   = (const float*)d_in[10];
    const float* unemb_w = (const float*)d_in[11];
    const float* unemb_b = (const float*)d_in[12];
    float* out = (float*)d_out;

    // ---- workspace carve ----
    char* p = (char*)d_ws;
    ushort_t* scratch = (ushort_t*)p; p += (size_t)BLROWS * 384 * 2;   // 25 MB (Aim / bf16 tmp)
    float* scale= (float*)p;   p += (size_t)BLROWS * 4;
    float* cdf  = (float*)p;   p += (size_t)32 * NCH * 4;
    float* sbuf = (float*)p;   p += (size_t)32 * NCH * 1024 * 4;       // 16.8 MB
    float* hin  = (float*)p;   p += (size_t)32 * NCH * 1024 * 4;       // 16.8 MB
    float* brec = (float*)p;   p += (size_t)BLROWS * RECW * 4;         // 6.3 MB
    ushort_t* Wt_p   = (ushort_t*)p; p += (size_t)256 * 384 * 2;
    ushort_t* Wt_in  = (ushort_t*)p; p += (size_t)1152 * 256 * 2;
    ushort_t* Wt_out = (ushort_t*)p; p += (size_t)256 * 512 * 2;
    ushort_t* Wt_un  = (ushort_t*)p; p += (size_t)384 * 256 * 2;
    ushort_t* xs     = (ushort_t*)p; p += (size_t)BLROWS * DM_ * 2;    // 16.8 MB
    ushort_t* xbc    = (ushort_t*)p; p += (size_t)BLROWS * 512 * 2;    // 33.5 MB
    ushort_t* z_bf   = (ushort_t*)p; p += (size_t)BLROWS * 512 * 2;    // 33.5 MB
    ushort_t* xbcdt  = (ushort_t*)p; p += (size_t)BLROWS * 640 * 2;    // 41.9 MB (later: yg)
    size_t need = (size_t)(p - (char*)d_ws);
    if (ws_size < need) return;

    ushort_t* Aim = scratch;            // im2col (dead after patch GEMM)
    ushort_t* tmp = scratch;            // bf16 unembed output (dead until unembed)
    ushort_t* yg  = xbcdt;              // yg overlays xbcdt (dead after conv)

    k_castpad<<<256, 384, 0, stream>>>(patch_w, Wt_p);
    k_transcast<<<1152, 256, 0, stream>>>(W_in, Wt_in, 256, 1064, nullptr);
    k_transcast<<<256, 256, 0, stream>>>(W_out, Wt_out, 512, 256, norm_w);  // fold RMSNorm weight
    k_transcast<<<384, 256, 0, stream>>>(unemb_w, Wt_un, 256, 368, nullptr);

    k_im2col<<<dim3(32, 8, 4), 256, 0, stream>>>(x, Aim);
    k_mgemm<384, 256, true><<<dim3(2, 256), 256, 0, stream>>>(Aim, 384, Wt_p, xs, 256, 0, patch_b, nullptr);

    // in-proj split: z cols 0..511 -> z_bf; xBC+dt cols 512..1063 -> xbcdt
    k_mgemm<256, 512, true><<<dim3(4, 256), 256, 0, stream>>>(xs, 256, Wt_in, z_bf, 512, 0, nullptr, nullptr);
    k_mgemm<256, 552, true><<<dim3(5, 256), 256, 0, stream>>>(xs, 256, Wt_in + (size_t)512 * 256, xbcdt, 640, 0, nullptr, nullptr);

    k_conv<<<BLROWS / 8, 256, 0, stream>>>(xbcdt, conv_w, conv_b, dt_bias, A_log, xbc, brec, nullptr, nullptr);

    k_scan1<<<dim3(NCH, 2, 4), 256, 0, stream>>>(xbc, brec, sbuf, cdf);
    k_chain<<<dim3(8, 4), 256, 0, stream>>>(sbuf, cdf, hin);
    k_scan2<<<dim3(NCH, 4), 512, 0, stream>>>(xbc, z_bf, brec, D_param, hin, yg);
    k_rsum<<<BLROWS / 4, 256, 0, stream>>>(yg, scale);

    // out-proj with fused RMSNorm row-scale: out_seq bf16 -> xs
    k_mgemm<512, 256, true><<<dim3(2, 256), 256, 0, stream>>>(yg, 512, Wt_out, xs, DM_, 0, nullptr, scale);

    k_mgemm<256, 368, true><<<dim3(3, 256), 256, 0, stream>>>(xs, 256, Wt_un, tmp, KPATCH, 0, nullptr, nullptr);

    k_scatter<<<dim3(64, 184, 4), 256, 0, stream>>>(tmp, unemb_b, x, out);
}

// Round 11
// 275.503 us; speedup vs baseline: 1.0846x; 1.0540x over previous
//
#include <hip/hip_runtime.h>
#include <hip/hip_bf16.h>
#include <cstdint>
#include <cstddef>

// ---- problem constants ----
#define B_N       4
#define C_INCH    23
#define T_N       8
#define W_IMG     128
#define L_SEQ     8192
#define BLROWS    32768      // B_N * L_SEQ
#define DM_       256
#define D_INNER_  512
#define CONV_DIM_ 544
#define D_PROJ    1064
#define KPATCH    368        // C_INCH*4*4
#define QCH       64         // scan chunk length
#define NCH       128        // chunks per batch
#define RECW      48         // packed scan record width (floats): B16 C16 dA8 dt8
#define PFD       8          // scan prefetch depth (steps)

typedef unsigned short ushort_t;
typedef unsigned int uint_t;
typedef __attribute__((ext_vector_type(8))) short short8;
typedef __attribute__((ext_vector_type(4))) float f32x4;

__device__ __forceinline__ float b2f(ushort_t u) {
    union { float f; uint_t u; } v; v.u = ((uint_t)u) << 16; return v.f;
}
__device__ __forceinline__ ushort_t f2b(float f) {
    union { float f; uint_t u; } v; v.f = f;
    uint_t r = v.u + 0x7fffu + ((v.u >> 16) & 1u);
    return (ushort_t)(r >> 16);
}

// async global->LDS, 16B per lane. LDS dest = wave-uniform base + lane*16.
__device__ __forceinline__ void gload_lds16(const ushort_t* g, ushort_t* l) {
    __builtin_amdgcn_global_load_lds(
        (const __attribute__((address_space(1))) unsigned int*)g,
        (__attribute__((address_space(3))) unsigned int*)l, 16, 0, 0);
}

// ---------------------------------------------------------------
// weight prep: dst[Npad][K] bf16 = transpose(src[K][N] fp32) * (rscale?rscale[k]:1)
__global__ void k_transcast(const float* __restrict__ src, ushort_t* __restrict__ dst,
                            int K, int N, const float* __restrict__ rscale) {
    int n = blockIdx.x;
    for (int k = threadIdx.x; k < K; k += 256) {
        float v = 0.f;
        if (n < N) {
            v = src[(size_t)k * N + n];
            if (rscale) v *= rscale[k];
        }
        dst[(size_t)n * K + k] = f2b(v);
    }
}

// patch weights are already [d][k]: direct cast + pad k to 384
__global__ void k_castpad(const float* __restrict__ src, ushort_t* __restrict__ dst) {
    int d = blockIdx.x; int k = threadIdx.x;   // 384 threads
    dst[d * 384 + k] = (k < KPATCH) ? f2b(src[d * KPATCH + k]) : (ushort_t)0;
}

// ---------------------------------------------------------------
// im2col gather: Aim[row][384] bf16, row=(b,t,hp,wp), kk=c*16+i*4+j; kk>=368 -> 0
__global__ void __launch_bounds__(256) k_im2col(const float* __restrict__ x,
                                                ushort_t* __restrict__ Aim) {
    int hp = blockIdx.x, t = blockIdx.y, b = blockIdx.z;
    int tid = threadIdx.x;
    int half = tid >> 7, q = tid & 127;
    int wp = q >> 2, j = q & 3;
    size_t rowbase = (size_t)b * L_SEQ + t * 1024 + hp * 32;
    #pragma unroll
    for (int it = 0; it < 2; ++it) {
        int idx = it * 256 + tid;
        int wpz = idx >> 4, kz = KPATCH + (idx & 15);
        Aim[(rowbase + wpz) * 384 + kz] = 0;
    }
    for (int s2 = 0; s2 < 46; ++s2) {
        int seg = s2 * 2 + half;            // c*4+i
        int c = seg >> 2, i = seg & 3;
        float v = x[(((size_t)(b * C_INCH + c) * T_N + t) << 14) + (size_t)(hp * 4 + i) * W_IMG + q];
        Aim[(rowbase + wp) * 384 + c * 16 + i * 4 + j] = f2b(v);
    }
}

// ---------------------------------------------------------------
// MFMA GEMM: C[M,N] = A[M,K](bf16) @ Wt[n][k](bf16, padded rows) [+bias[n]] [*rowscale[m]].
// 128x128 tile, 4 waves (2x2 of 64x64), BK=64, global_load_lds staging, XOR-swizzled LDS.
template <int K, int N, bool CBF>
__global__ void __launch_bounds__(256) k_mgemm(const ushort_t* __restrict__ A, const int lda,
                                               const ushort_t* __restrict__ Wt,
                                               void* __restrict__ Cv, const int ldc, const int coff,
                                               const float* __restrict__ bias,
                                               const float* __restrict__ rowscale) {
    __shared__ ushort_t Al[128 * 64];
    __shared__ ushort_t Bl[128 * 64];
    const int tid = threadIdx.x;
    const int w = tid >> 6, lane = tid & 63;
    const int wr = w >> 1, wc = w & 1;
    const int rowbase = blockIdx.y * 128;
    const int colbase = blockIdx.x * 128;
    const int g = lane >> 4, r = lane & 15;

    f32x4 acc[4][4];
    #pragma unroll
    for (int i = 0; i < 4; ++i)
        #pragma unroll
        for (int j = 0; j < 4; ++j) acc[i][j] = (f32x4){0.f, 0.f, 0.f, 0.f};

    for (int k0 = 0; k0 < K; k0 += 64) {
        __syncthreads();
        #pragma unroll
        for (int it = 0; it < 4; ++it) {
            int s = it * 256 + (w << 6) + lane;
            int row = s >> 3;
            int c16 = (s & 7) ^ (row & 7);
            gload_lds16(A + (size_t)(rowbase + row) * lda + k0 + c16 * 8,
                        &Al[(size_t)(it * 256 + (w << 6)) * 8]);
        }
        #pragma unroll
        for (int it = 0; it < 4; ++it) {
            int s = it * 256 + (w << 6) + lane;
            int row = s >> 3;
            int c16 = (s & 7) ^ (row & 7);
            gload_lds16(Wt + (size_t)(colbase + row) * K + k0 + c16 * 8,
                        &Bl[(size_t)(it * 256 + (w << 6)) * 8]);
        }
        __syncthreads();

        short8 af[2][4], bf[2][4];
        #pragma unroll
        for (int ks = 0; ks < 2; ++ks)
            #pragma unroll
            for (int mi = 0; mi < 4; ++mi) {
                int row = (wr << 6) + (mi << 4) + r;
                int c16 = ((ks << 2) | g) ^ (row & 7);
                af[ks][mi] = *(const short8*)&Al[(size_t)((row << 3) + c16) * 8];
            }
        #pragma unroll
        for (int ks = 0; ks < 2; ++ks)
            #pragma unroll
            for (int ni = 0; ni < 4; ++ni) {
                int row = (wc << 6) + (ni << 4) + r;
                int c16 = ((ks << 2) | g) ^ (row & 7);
                bf[ks][ni] = *(const short8*)&Bl[(size_t)((row << 3) + c16) * 8];
            }
        #pragma unroll
        for (int ks = 0; ks < 2; ++ks)
            #pragma unroll
            for (int mi = 0; mi < 4; ++mi)
                #pragma unroll
                for (int ni = 0; ni < 4; ++ni)
                    acc[mi][ni] = __builtin_amdgcn_mfma_f32_16x16x32_bf16(
                        af[ks][mi], bf[ks][ni], acc[mi][ni], 0, 0, 0);
    }

    // C store: D col=lane&15, row=(lane>>4)*4+reg
    #pragma unroll
    for (int mi = 0; mi < 4; ++mi) {
        int rw = rowbase + (wr << 6) + (mi << 4) + (g << 2);
        float s0 = 1.f, s1 = 1.f, s2 = 1.f, s3 = 1.f;
        if (rowscale) { s0 = rowscale[rw]; s1 = rowscale[rw+1]; s2 = rowscale[rw+2]; s3 = rowscale[rw+3]; }
        #pragma unroll
        for (int ni = 0; ni < 4; ++ni) {
            int col = colbase + (wc << 6) + (ni << 4) + r;
            if (col < N) {
                float bv = bias ? bias[col] : 0.f;
                f32x4 v = acc[mi][ni];
                float vr[4] = {v[0]*s0 + bv, v[1]*s1 + bv, v[2]*s2 + bv, v[3]*s3 + bv};
                #pragma unroll
                for (int j = 0; j < 4; ++j) {
                    size_t cidx = (size_t)(rw + j) * ldc + coff + col;
                    if (CBF) ((ushort_t*)Cv)[cidx] = f2b(vr[j]);
                    else     ((float*)Cv)[cidx]   = vr[j];
                }
            }
        }
    }
}

// ---------------------------------------------------------------
// causal depthwise conv (kernel 4) + silu, sliding-window over 8 rows/block.
// ch<512 -> xbc bf16; 512..543 (B,C) -> brec[row][0..31]; dt -> brec[row][32+h]=dA, [40+h]=dt.
__global__ void __launch_bounds__(256) k_conv(const ushort_t* __restrict__ xbcdt,
                                              const float* __restrict__ cw,
                                              const float* __restrict__ cb,
                                              const float* __restrict__ dtb,
                                              const float* __restrict__ alog,
                                              ushort_t* __restrict__ xbc,
                                              float* __restrict__ brec) {
    int tid = threadIdx.x;
    int rb = blockIdx.x * 8;            // first row of this block
    int srb = rb & (L_SEQ - 1);         // seq pos within batch
    #pragma unroll
    for (int it = 0; it < 3; ++it) {
        int ch = it * 256 + tid;
        if (ch >= 552) break;
        if (ch < CONV_DIM_) {
            float w0 = cw[ch * 4 + 0], w1 = cw[ch * 4 + 1];
            float w2 = cw[ch * 4 + 2], w3 = cw[ch * 4 + 3];
            float bias = cb[ch];
            float win[11];
            #pragma unroll
            for (int j = 0; j < 11; ++j) {
                int sj = srb + j - 3;
                win[j] = (sj >= 0) ? b2f(xbcdt[(size_t)(rb + j - 3) * 640 + ch]) : 0.f;
            }
            #pragma unroll
            for (int r = 0; r < 8; ++r) {
                float acc = bias + win[r] * w0 + win[r + 1] * w1 + win[r + 2] * w2 + win[r + 3] * w3;
                float s = acc / (1.f + __expf(-acc));
                size_t row = rb + r;
                if (ch < 512) xbc[row * 512 + ch] = f2b(s);
                else          brec[row * RECW + (ch - 512)] = s;
            }
        } else {
            int h = ch - CONV_DIM_;
            float A = -__expf(alog[h]);
            float db = dtb[h];
            #pragma unroll
            for (int r = 0; r < 8; ++r) {
                size_t row = rb + r;
                float v = b2f(xbcdt[row * 640 + ch]) + db;
                float sp = (v > 20.f) ? v : log1pf(__expf(v));
                brec[row * RECW + 32 + h] = __expf(sp * A);   // dA
                brec[row * RECW + 40 + h] = sp;               // dt
            }
        }
    }
}

// ---------------------------------------------------------------
// scan phase 1: chunk-final local states ONLY + per-chunk decay.
// Records staged in LDS; xh batch-prefetched PFD steps deep.
// block = 4 heads x 64 p; grid (NCH, 2, B).
__global__ void __launch_bounds__(256) k_scan1(const ushort_t* __restrict__ xbc,
                                               const float* __restrict__ brec,
                                               float* __restrict__ sbuf,
                                               float* __restrict__ cdf) {
    __shared__ float rec[QCH * RECW];     // 12 KB
    int c = blockIdx.x, b = blockIdx.z;
    int tid = threadIdx.x;
    int h = blockIdx.y * 4 + (tid >> 6);
    int p = tid & 63;
    int off = h * 64 + p;
    size_t row0 = (size_t)b * L_SEQ + (size_t)c * QCH;

    // stage chunk records: QCH*RECW/4 = 768 float4
    {
        const float4* src = (const float4*)(brec + row0 * RECW);
        float4* dst = (float4*)rec;
        #pragma unroll
        for (int i = 0; i < 3; ++i) dst[i * 256 + tid] = src[i * 256 + tid];
    }

    float st[16];
    #pragma unroll
    for (int n = 0; n < 16; ++n) st[n] = 0.f;
    float cd = 1.f;
    float xh[PFD];
    #pragma unroll
    for (int j = 0; j < PFD; ++j) xh[j] = b2f(xbc[(row0 + j) * 512 + off]);
    __syncthreads();

    for (int s0 = 0; s0 < QCH; s0 += PFD) {
        float xhn[PFD];
        #pragma unroll
        for (int j = 0; j < PFD; ++j)
            xhn[j] = b2f(xbc[(row0 + s0 + PFD + j) * 512 + off]);  // final-batch overread stays in d_ws: safe
        #pragma unroll
        for (int j = 0; j < PFD; ++j) {
            const float* r = rec + (s0 + j) * RECW;
            float da  = r[32 + h];
            float dtt = r[40 + h];
            float xdt = xh[j] * dtt;
            const float4* B4 = (const float4*)r;
            #pragma unroll
            for (int q = 0; q < 4; ++q) {
                float4 Bv = B4[q];
                st[q*4+0] = da * st[q*4+0] + xdt * Bv.x;
                st[q*4+1] = da * st[q*4+1] + xdt * Bv.y;
                st[q*4+2] = da * st[q*4+2] + xdt * Bv.z;
                st[q*4+3] = da * st[q*4+3] + xdt * Bv.w;
            }
            cd *= da;
        }
        #pragma unroll
        for (int j = 0; j < PFD; ++j) xh[j] = xhn[j];
    }
    size_t base = (size_t)((b * 8 + h) * NCH + c) * 1024 + p * 16;
    #pragma unroll
    for (int q = 0; q < 4; ++q)
        *(float4*)&sbuf[base + q * 4] = make_float4(st[q*4], st[q*4+1], st[q*4+2], st[q*4+3]);
    if (p == 0) cdf[(b * 8 + h) * NCH + c] = cd;
}

// ---------------------------------------------------------------
// phase 2: sequential chain over chunks (tiny). block = (h, b); thread holds 4 states.
__global__ void __launch_bounds__(256) k_chain(const float* __restrict__ sbuf,
                                               const float* __restrict__ cdf,
                                               float* __restrict__ hin) {
    int h = blockIdx.x, b = blockIdx.y;
    int tid = threadIdx.x;
    float4 H = make_float4(0.f, 0.f, 0.f, 0.f);
    size_t base = (size_t)((b * 8 + h) * NCH) * 1024;
    for (int c = 0; c < NCH; ++c) {
        *(float4*)&hin[base + (size_t)c * 1024 + tid * 4] = H;
        float cdfv = cdf[(b * 8 + h) * NCH + c];
        float4 S = *(const float4*)&sbuf[base + (size_t)c * 1024 + tid * 4];
        H.x = cdfv * H.x + S.x;
        H.y = cdfv * H.y + S.y;
        H.z = cdfv * H.z + S.z;
        H.w = cdfv * H.w + S.w;
    }
}

// ---------------------------------------------------------------
// scan phase 3: full re-scan from Hin (exact y) + gate -> yg buffer.
// Records in LDS; xh/zz batch-prefetched PFD deep. block = 8 heads x 64 p; grid (NCH, B).
__global__ void __launch_bounds__(512) k_scan2(const ushort_t* __restrict__ xbc,
                                               const ushort_t* __restrict__ z_bf,
                                               const float* __restrict__ brec,
                                               const float* __restrict__ Dp,
                                               const float* __restrict__ hin,
                                               ushort_t* __restrict__ yg_out) {
    __shared__ float rec[QCH * RECW];     // 12 KB
    int c = blockIdx.x, b = blockIdx.y;
    int tid = threadIdx.x;
    int h = tid >> 6, p = tid & 63;
    int off = h * 64 + p;
    size_t row0 = (size_t)b * L_SEQ + (size_t)c * QCH;

    // stage chunk records: 768 float4, 512 threads
    {
        const float4* src = (const float4*)(brec + row0 * RECW);
        float4* dst = (float4*)rec;
        dst[tid] = src[tid];
        if (tid < 256) dst[512 + tid] = src[512 + tid];
    }

    float st[16];
    const float4* H = (const float4*)&hin[(size_t)((b * 8 + h) * NCH + c) * 1024 + p * 16];
    #pragma unroll
    for (int q = 0; q < 4; ++q) {
        float4 Hv = H[q];
        st[q*4+0] = Hv.x; st[q*4+1] = Hv.y; st[q*4+2] = Hv.z; st[q*4+3] = Hv.w;
    }
    float Dh = Dp[h];
    float xh[PFD], zz[PFD];
    #pragma unroll
    for (int j = 0; j < PFD; ++j) {
        xh[j] = b2f(xbc[(row0 + j) * 512 + off]);
        zz[j] = b2f(z_bf[(row0 + j) * 512 + off]);
    }
    __syncthreads();

    for (int s0 = 0; s0 < QCH; s0 += PFD) {
        float xhn[PFD], zzn[PFD];
        #pragma unroll
        for (int j = 0; j < PFD; ++j) {
            size_t rn = row0 + s0 + PFD + j;     // final-batch overread stays in d_ws: safe
            xhn[j] = b2f(xbc[rn * 512 + off]);
            zzn[j] = b2f(z_bf[rn * 512 + off]);
        }
        #pragma unroll
        for (int j = 0; j < PFD; ++j) {
            const float* r = rec + (s0 + j) * RECW;
            float da  = r[32 + h];
            float dtt = r[40 + h];
            float xdt = xh[j] * dtt;
            const float4* B4 = (const float4*)r;
            const float4* C4 = (const float4*)(r + 16);
            float d0 = 0.f, d1 = 0.f, d2 = 0.f, d3 = 0.f;
            #pragma unroll
            for (int q = 0; q < 4; ++q) {
                float4 Bv = B4[q];
                float4 Cv = C4[q];
                st[q*4+0] = da * st[q*4+0] + xdt * Bv.x;
                st[q*4+1] = da * st[q*4+1] + xdt * Bv.y;
                st[q*4+2] = da * st[q*4+2] + xdt * Bv.z;
                st[q*4+3] = da * st[q*4+3] + xdt * Bv.w;
                d0 += st[q*4+0] * Cv.x;
                d1 += st[q*4+1] * Cv.y;
                d2 += st[q*4+2] * Cv.z;
                d3 += st[q*4+3] * Cv.w;
            }
            float y = (d0 + d1) + (d2 + d3) + Dh * xh[j];
            float ygv = y * (zz[j] / (1.f + __expf(-zz[j])));
            yg_out[(row0 + s0 + j) * 512 + off] = f2b(ygv);
        }
        #pragma unroll
        for (int j = 0; j < PFD; ++j) { xh[j] = xhn[j]; zz[j] = zzn[j]; }
    }
}

// ---------------------------------------------------------------
// row scale from yg: scale[row] = rsqrt(mean(yg^2) + eps). one wave per row.
__global__ void __launch_bounds__(256) k_rsum(const ushort_t* __restrict__ yg,
                                              float* __restrict__ scale) {
    int wid = threadIdx.x >> 6, lane = threadIdx.x & 63;
    int row = blockIdx.x * 4 + wid;
    short8 v = *(const short8*)&yg[(size_t)row * 512 + lane * 8];
    float s = 0.f;
    #pragma unroll
    for (int j = 0; j < 8; ++j) {
        float f = b2f((ushort_t)v[j]);
        s += f * f;
    }
    #pragma unroll
    for (int off = 32; off >= 1; off >>= 1) s += __shfl_xor(s, off);
    if (lane == 0) scale[row] = rsqrtf(s * (1.f / 512.f) + 1e-5f);
}

// ---------------------------------------------------------------
__global__ void __launch_bounds__(256) k_scatter(const ushort_t* __restrict__ tmp,
                                                 const float* __restrict__ ub,
                                                 const float* __restrict__ xin,
                                                 float* __restrict__ out) {
    int tid = threadIdx.x;
    int w = tid & 127;
    int h = (blockIdx.x << 1) | (tid >> 7);
    int c = blockIdx.y >> 3, t = blockIdx.y & 7;
    int b = blockIdx.z;
    size_t row = (size_t)b * L_SEQ + t * 1024 + (h >> 2) * 32 + (w >> 2);
    int kk = c * 16 + (h & 3) * 4 + (w & 3);
    size_t oidx = (((size_t)(b * C_INCH + c) * T_N + t) << 14) + (size_t)h * W_IMG + w;
    out[oidx] = b2f(tmp[row * KPATCH + kk]) + ub[c] + xin[oidx];
}

// ---------------------------------------------------------------
extern "C" void kernel_launch(void* const* d_in, const int* in_sizes, int n_in,
                              void* d_out, int out_size, void* d_ws, size_t ws_size,
                              hipStream_t stream) {
    const float* x       = (const float*)d_in[0];
    const float* patch_w = (const float*)d_in[1];
    const float* patch_b = (const float*)d_in[2];
    const float* W_in    = (const float*)d_in[3];
    const float* conv_w  = (const float*)d_in[4];
    const float* conv_b  = (const float*)d_in[5];
    const float* dt_bias = (const float*)d_in[6];
    const float* A_log   = (const float*)d_in[7];
    const float* D_param = (const float*)d_in[8];
    const float* norm_w  = (const float*)d_in[9];
    const float* W_out   = (const float*)d_in[10];
    const float* unemb_w = (const float*)d_in[11];
    const float* unemb_b = (const float*)d_in[12];
    float* out = (float*)d_out;

    // ---- workspace carve ----
    char* p = (char*)d_ws;
    ushort_t* scratch = (ushort_t*)p; p += (size_t)BLROWS * 384 * 2;   // 25 MB (Aim / bf16 tmp)
    float* scale= (float*)p;   p += (size_t)BLROWS * 4;
    float* cdf  = (float*)p;   p += (size_t)32 * NCH * 4;
    float* sbuf = (float*)p;   p += (size_t)32 * NCH * 1024 * 4;       // 16.8 MB
    float* hin  = (float*)p;   p += (size_t)32 * NCH * 1024 * 4;       // 16.8 MB
    float* brec = (float*)p;   p += (size_t)BLROWS * RECW * 4;         // 6.3 MB
    ushort_t* Wt_p   = (ushort_t*)p; p += (size_t)256 * 384 * 2;
    ushort_t* Wt_in  = (ushort_t*)p; p += (size_t)1152 * 256 * 2;
    ushort_t* Wt_out = (ushort_t*)p; p += (size_t)256 * 512 * 2;
    ushort_t* Wt_un  = (ushort_t*)p; p += (size_t)384 * 256 * 2;
    ushort_t* xs     = (ushort_t*)p; p += (size_t)BLROWS * DM_ * 2;    // 16.8 MB
    ushort_t* xbc    = (ushort_t*)p; p += (size_t)BLROWS * 512 * 2;    // 33.5 MB
    ushort_t* z_bf   = (ushort_t*)p; p += (size_t)BLROWS * 512 * 2;    // 33.5 MB
    ushort_t* xbcdt  = (ushort_t*)p; p += (size_t)BLROWS * 640 * 2;    // 41.9 MB (later: yg)
    size_t need = (size_t)(p - (char*)d_ws);
    if (ws_size < need) return;

    ushort_t* Aim = scratch;            // im2col (dead after patch GEMM)
    ushort_t* tmp = scratch;            // bf16 unembed output (dead until unembed)
    ushort_t* yg  = xbcdt;              // yg overlays xbcdt (dead after conv)

    k_castpad<<<256, 384, 0, stream>>>(patch_w, Wt_p);
    k_transcast<<<1152, 256, 0, stream>>>(W_in, Wt_in, 256, 1064, nullptr);
    k_transcast<<<256, 256, 0, stream>>>(W_out, Wt_out, 512, 256, norm_w);  // fold RMSNorm weight
    k_transcast<<<384, 256, 0, stream>>>(unemb_w, Wt_un, 256, 368, nullptr);

    k_im2col<<<dim3(32, 8, 4), 256, 0, stream>>>(x, Aim);
    k_mgemm<384, 256, true><<<dim3(2, 256), 256, 0, stream>>>(Aim, 384, Wt_p, xs, 256, 0, patch_b, nullptr);

    // in-proj split: z cols 0..511 -> z_bf; xBC+dt cols 512..1063 -> xbcdt
    k_mgemm<256, 512, true><<<dim3(4, 256), 256, 0, stream>>>(xs, 256, Wt_in, z_bf, 512, 0, nullptr, nullptr);
    k_mgemm<256, 552, true><<<dim3(5, 256), 256, 0, stream>>>(xs, 256, Wt_in + (size_t)512 * 256, xbcdt, 640, 0, nullptr, nullptr);

    k_conv<<<BLROWS / 8, 256, 0, stream>>>(xbcdt, conv_w, conv_b, dt_bias, A_log, xbc, brec);

    k_scan1<<<dim3(NCH, 2, 4), 256, 0, stream>>>(xbc, brec, sbuf, cdf);
    k_chain<<<dim3(8, 4), 256, 0, stream>>>(sbuf, cdf, hin);
    k_scan2<<<dim3(NCH, 4), 512, 0, stream>>>(xbc, z_bf, brec, D_param, hin, yg);
    k_rsum<<<BLROWS / 4, 256, 0, stream>>>(yg, scale);

    // out-proj with fused RMSNorm row-scale: out_seq bf16 -> xs
    k_mgemm<512, 256, true><<<dim3(2, 256), 256, 0, stream>>>(yg, 512, Wt_out, xs, DM_, 0, nullptr, scale);

    k_mgemm<256, 368, true><<<dim3(3, 256), 256, 0, stream>>>(xs, 256, Wt_un, tmp, KPATCH, 0, nullptr, nullptr);

    k_scatter<<<dim3(64, 184, 4), 256, 0, stream>>>(tmp, unemb_b, x, out);
}

// Round 12
// 259.644 us; speedup vs baseline: 1.1508x; 1.0611x over previous
//
#include <hip/hip_runtime.h>
#include <hip/hip_bf16.h>
#include <cstdint>
#include <cstddef>

// ---- problem constants ----
#define B_N       4
#define C_INCH    23
#define T_N       8
#define W_IMG     128
#define L_SEQ     8192
#define BLROWS    32768      // B_N * L_SEQ
#define DM_       256
#define D_INNER_  512
#define CONV_DIM_ 544
#define D_PROJ    1064
#define KPATCH    368        // C_INCH*4*4
#define QCH       64         // scan chunk length
#define NCH       128        // chunks per batch
#define RECW      48         // packed scan record width (floats): B16 C16 dA8 dt8
#define PFD       8          // scan prefetch depth (steps)

typedef unsigned short ushort_t;
typedef unsigned int uint_t;
typedef __attribute__((ext_vector_type(8))) short short8;
typedef __attribute__((ext_vector_type(4))) float f32x4;

__device__ __forceinline__ float b2f(ushort_t u) {
    union { float f; uint_t u; } v; v.u = ((uint_t)u) << 16; return v.f;
}
__device__ __forceinline__ ushort_t f2b(float f) {
    union { float f; uint_t u; } v; v.f = f;
    uint_t r = v.u + 0x7fffu + ((v.u >> 16) & 1u);
    return (ushort_t)(r >> 16);
}

// async global->LDS, 16B per lane. LDS dest = wave-uniform base + lane*16.
__device__ __forceinline__ void gload_lds16(const ushort_t* g, ushort_t* l) {
    __builtin_amdgcn_global_load_lds(
        (const __attribute__((address_space(1))) unsigned int*)g,
        (__attribute__((address_space(3))) unsigned int*)l, 16, 0, 0);
}

// ---------------------------------------------------------------
// weight prep: dst[Npad][K] bf16 = transpose(src[K][N] fp32) * (rscale?rscale[k]:1)
__global__ void k_transcast(const float* __restrict__ src, ushort_t* __restrict__ dst,
                            int K, int N, const float* __restrict__ rscale) {
    int n = blockIdx.x;
    for (int k = threadIdx.x; k < K; k += 256) {
        float v = 0.f;
        if (n < N) {
            v = src[(size_t)k * N + n];
            if (rscale) v *= rscale[k];
        }
        dst[(size_t)n * K + k] = f2b(v);
    }
}

// patch weights are already [d][k]: direct cast + pad k to 384
__global__ void k_castpad(const float* __restrict__ src, ushort_t* __restrict__ dst) {
    int d = blockIdx.x; int k = threadIdx.x;   // 384 threads
    dst[d * 384 + k] = (k < KPATCH) ? f2b(src[d * KPATCH + k]) : (ushort_t)0;
}

// ---------------------------------------------------------------
// fused patch-embed GEMM: xs[BL,256] = gather-im2col(x)[BL,384] @ Wt_p[256][384] + pb.
// A gathered from x directly (no materialized im2col). 128x128 tile, BK=64.
__global__ void __launch_bounds__(256) k_pgemm(const float* __restrict__ x,
                                               const ushort_t* __restrict__ Wt,
                                               ushort_t* __restrict__ Cv,
                                               const float* __restrict__ bias) {
    __shared__ ushort_t Al[128 * 64];
    __shared__ ushort_t Bl[128 * 64];
    const int tid = threadIdx.x;
    const int w = tid >> 6, lane = tid & 63;
    const int wr = w >> 1, wc = w & 1;
    const int rowbase = blockIdx.y * 128;
    const int colbase = blockIdx.x * 128;
    const int g = lane >> 4, r = lane & 15;
    const int b  = rowbase >> 13;
    const int t  = (rowbase >> 10) & 7;
    const int hp0 = (rowbase >> 5) & 31;   // multiple of 4

    f32x4 acc[4][4];
    #pragma unroll
    for (int i = 0; i < 4; ++i)
        #pragma unroll
        for (int j = 0; j < 4; ++j) acc[i][j] = (f32x4){0.f, 0.f, 0.f, 0.f};

    for (int it = 0; it < 6; ++it) {        // K=384, BK=64
        int k0 = it * 64;
        __syncthreads();
        // B tile via async gload (XOR-swizzled 16B slots)
        #pragma unroll
        for (int i2 = 0; i2 < 4; ++i2) {
            int s = i2 * 256 + (w << 6) + lane;
            int row = s >> 3;
            int c16 = (s & 7) ^ (row & 7);
            gload_lds16(Wt + (size_t)(colbase + row) * 384 + k0 + c16 * 8,
                        &Bl[(size_t)(i2 * 256 + (w << 6)) * 8]);
        }
        // A tile: gather 4 fp32 (one j-quad) per slot-half, cvt, swizzled ds_write_b64
        #pragma unroll
        for (int i2 = 0; i2 < 8; ++i2) {
            int idx = i2 * 256 + tid;          // 0..2047 = row*16 + kq
            int row = idx >> 4, kq = idx & 15; // k = k0 + kq*4
            int c = (k0 >> 4) + (kq >> 2);     // c = 4*it + kq>>2
            int i = kq & 3;
            uint_t u0 = 0, u1 = 0;
            if (c < C_INCH) {
                int hp = hp0 + (row >> 5), wp = row & 31;
                const float4 v = *(const float4*)&x[(((size_t)(b * C_INCH + c) * T_N + t) << 14)
                                                    + (size_t)(hp * 4 + i) * W_IMG + wp * 4];
                u0 = (uint_t)f2b(v.x) | ((uint_t)f2b(v.y) << 16);
                u1 = (uint_t)f2b(v.z) | ((uint_t)f2b(v.w) << 16);
            }
            int slot = (row << 3) + ((kq >> 1) ^ (row & 7));
            *(uint2*)&Al[(size_t)slot * 8 + (kq & 1) * 4] = make_uint2(u0, u1);
        }
        __syncthreads();

        short8 af[2][4], bf[2][4];
        #pragma unroll
        for (int ks = 0; ks < 2; ++ks)
            #pragma unroll
            for (int mi = 0; mi < 4; ++mi) {
                int row = (wr << 6) + (mi << 4) + r;
                int c16 = ((ks << 2) | g) ^ (row & 7);
                af[ks][mi] = *(const short8*)&Al[(size_t)((row << 3) + c16) * 8];
            }
        #pragma unroll
        for (int ks = 0; ks < 2; ++ks)
            #pragma unroll
            for (int ni = 0; ni < 4; ++ni) {
                int row = (wc << 6) + (ni << 4) + r;
                int c16 = ((ks << 2) | g) ^ (row & 7);
                bf[ks][ni] = *(const short8*)&Bl[(size_t)((row << 3) + c16) * 8];
            }
        #pragma unroll
        for (int ks = 0; ks < 2; ++ks)
            #pragma unroll
            for (int mi = 0; mi < 4; ++mi)
                #pragma unroll
                for (int ni = 0; ni < 4; ++ni)
                    acc[mi][ni] = __builtin_amdgcn_mfma_f32_16x16x32_bf16(
                        af[ks][mi], bf[ks][ni], acc[mi][ni], 0, 0, 0);
    }

    #pragma unroll
    for (int mi = 0; mi < 4; ++mi) {
        int rw = rowbase + (wr << 6) + (mi << 4) + (g << 2);
        #pragma unroll
        for (int ni = 0; ni < 4; ++ni) {
            int col = colbase + (wc << 6) + (ni << 4) + r;
            float bv = bias[col];
            f32x4 v = acc[mi][ni];
            #pragma unroll
            for (int j = 0; j < 4; ++j)
                Cv[(size_t)(rw + j) * DM_ + col] = f2b(v[j] + bv);
        }
    }
}

// ---------------------------------------------------------------
// MFMA GEMM: C[M,N] = A[M,K](bf16) @ Wt[n][k](bf16) [+bias[n]].
// ASCALE: compute per-row rsqrt(mean(A_row^2)+eps) in-kernel and scale C rows
// (fused RMSNorm for the out-projection; K must equal the full row width).
template <int K, int N, bool CBF, bool ASCALE>
__global__ void __launch_bounds__(256) k_mgemm(const ushort_t* __restrict__ A, const int lda,
                                               const ushort_t* __restrict__ Wt,
                                               void* __restrict__ Cv, const int ldc, const int coff,
                                               const float* __restrict__ bias) {
    __shared__ ushort_t Al[128 * 64];
    __shared__ ushort_t Bl[128 * 64];
    const int tid = threadIdx.x;
    const int w = tid >> 6, lane = tid & 63;
    const int wr = w >> 1, wc = w & 1;
    const int rowbase = blockIdx.y * 128;
    const int colbase = blockIdx.x * 128;
    const int g = lane >> 4, r = lane & 15;

    f32x4 acc[4][4];
    #pragma unroll
    for (int i = 0; i < 4; ++i)
        #pragma unroll
        for (int j = 0; j < 4; ++j) acc[i][j] = (f32x4){0.f, 0.f, 0.f, 0.f};
    float rs[4] = {0.f, 0.f, 0.f, 0.f};

    for (int k0 = 0; k0 < K; k0 += 64) {
        __syncthreads();
        #pragma unroll
        for (int it = 0; it < 4; ++it) {
            int s = it * 256 + (w << 6) + lane;
            int row = s >> 3;
            int c16 = (s & 7) ^ (row & 7);
            gload_lds16(A + (size_t)(rowbase + row) * lda + k0 + c16 * 8,
                        &Al[(size_t)(it * 256 + (w << 6)) * 8]);
        }
        #pragma unroll
        for (int it = 0; it < 4; ++it) {
            int s = it * 256 + (w << 6) + lane;
            int row = s >> 3;
            int c16 = (s & 7) ^ (row & 7);
            gload_lds16(Wt + (size_t)(colbase + row) * K + k0 + c16 * 8,
                        &Bl[(size_t)(it * 256 + (w << 6)) * 8]);
        }
        __syncthreads();

        short8 af[2][4], bf[2][4];
        #pragma unroll
        for (int ks = 0; ks < 2; ++ks)
            #pragma unroll
            for (int mi = 0; mi < 4; ++mi) {
                int row = (wr << 6) + (mi << 4) + r;
                int c16 = ((ks << 2) | g) ^ (row & 7);
                af[ks][mi] = *(const short8*)&Al[(size_t)((row << 3) + c16) * 8];
            }
        #pragma unroll
        for (int ks = 0; ks < 2; ++ks)
            #pragma unroll
            for (int ni = 0; ni < 4; ++ni) {
                int row = (wc << 6) + (ni << 4) + r;
                int c16 = ((ks << 2) | g) ^ (row & 7);
                bf[ks][ni] = *(const short8*)&Bl[(size_t)((row << 3) + c16) * 8];
            }
        if (ASCALE) {
            #pragma unroll
            for (int ks = 0; ks < 2; ++ks)
                #pragma unroll
                for (int mi = 0; mi < 4; ++mi)
                    #pragma unroll
                    for (int e = 0; e < 8; ++e) {
                        float v = b2f((ushort_t)af[ks][mi][e]);
                        rs[mi] += v * v;
                    }
        }
        #pragma unroll
        for (int ks = 0; ks < 2; ++ks)
            #pragma unroll
            for (int mi = 0; mi < 4; ++mi)
                #pragma unroll
                for (int ni = 0; ni < 4; ++ni)
                    acc[mi][ni] = __builtin_amdgcn_mfma_f32_16x16x32_bf16(
                        af[ks][mi], bf[ks][ni], acc[mi][ni], 0, 0, 0);
    }

    // C store: D col=lane&15, row=(lane>>4)*4+reg
    #pragma unroll
    for (int mi = 0; mi < 4; ++mi) {
        int rw = rowbase + (wr << 6) + (mi << 4) + (g << 2);
        float sj[4] = {1.f, 1.f, 1.f, 1.f};
        if (ASCALE) {
            float s = rs[mi];
            s += __shfl_xor(s, 16);
            s += __shfl_xor(s, 32);
            float sc = rsqrtf(s * (1.f / 512.f) + 1e-5f);   // scale for row ...+r
            #pragma unroll
            for (int j = 0; j < 4; ++j) sj[j] = __shfl(sc, 4 * g + j);
        }
        #pragma unroll
        for (int ni = 0; ni < 4; ++ni) {
            int col = colbase + (wc << 6) + (ni << 4) + r;
            if (col < N) {
                float bv = bias ? bias[col] : 0.f;
                f32x4 v = acc[mi][ni];
                #pragma unroll
                for (int j = 0; j < 4; ++j) {
                    size_t cidx = (size_t)(rw + j) * ldc + coff + col;
                    float vr = v[j] * sj[j] + bv;
                    if (CBF) ((ushort_t*)Cv)[cidx] = f2b(vr);
                    else     ((float*)Cv)[cidx]   = vr;
                }
            }
        }
    }
}

// ---------------------------------------------------------------
// causal depthwise conv (kernel 4) + silu, sliding-window over 8 rows/block.
// ch<512 -> xbc bf16; 512..543 (B,C) -> brec[row][0..31]; dt -> brec[row][32+h]=dA, [40+h]=dt.
__global__ void __launch_bounds__(256) k_conv(const ushort_t* __restrict__ xbcdt,
                                              const float* __restrict__ cw,
                                              const float* __restrict__ cb,
                                              const float* __restrict__ dtb,
                                              const float* __restrict__ alog,
                                              ushort_t* __restrict__ xbc,
                                              float* __restrict__ brec) {
    int tid = threadIdx.x;
    int rb = blockIdx.x * 8;            // first row of this block
    int srb = rb & (L_SEQ - 1);         // seq pos within batch
    #pragma unroll
    for (int it = 0; it < 3; ++it) {
        int ch = it * 256 + tid;
        if (ch >= 552) break;
        if (ch < CONV_DIM_) {
            float w0 = cw[ch * 4 + 0], w1 = cw[ch * 4 + 1];
            float w2 = cw[ch * 4 + 2], w3 = cw[ch * 4 + 3];
            float bias = cb[ch];
            float win[11];
            #pragma unroll
            for (int j = 0; j < 11; ++j) {
                int sj = srb + j - 3;
                win[j] = (sj >= 0) ? b2f(xbcdt[(size_t)(rb + j - 3) * 640 + ch]) : 0.f;
            }
            #pragma unroll
            for (int r = 0; r < 8; ++r) {
                float acc = bias + win[r] * w0 + win[r + 1] * w1 + win[r + 2] * w2 + win[r + 3] * w3;
                float s = acc / (1.f + __expf(-acc));
                size_t row = rb + r;
                if (ch < 512) xbc[row * 512 + ch] = f2b(s);
                else          brec[row * RECW + (ch - 512)] = s;
            }
        } else {
            int h = ch - CONV_DIM_;
            float A = -__expf(alog[h]);
            float db = dtb[h];
            #pragma unroll
            for (int r = 0; r < 8; ++r) {
                size_t row = rb + r;
                float v = b2f(xbcdt[row * 640 + ch]) + db;
                float sp = (v > 20.f) ? v : log1pf(__expf(v));
                brec[row * RECW + 32 + h] = __expf(sp * A);   // dA
                brec[row * RECW + 40 + h] = sp;               // dt
            }
        }
    }
}

// ---------------------------------------------------------------
// scan phase 1: chunk-final local states ONLY + per-chunk decay.
// Records staged in LDS; xh batch-prefetched PFD steps deep.
// block = 4 heads x 64 p; grid (NCH, 2, B).
__global__ void __launch_bounds__(256) k_scan1(const ushort_t* __restrict__ xbc,
                                               const float* __restrict__ brec,
                                               float* __restrict__ sbuf,
                                               float* __restrict__ cdf) {
    __shared__ float rec[QCH * RECW];     // 12 KB
    int c = blockIdx.x, b = blockIdx.z;
    int tid = threadIdx.x;
    int h = blockIdx.y * 4 + (tid >> 6);
    int p = tid & 63;
    int off = h * 64 + p;
    size_t row0 = (size_t)b * L_SEQ + (size_t)c * QCH;

    {
        const float4* src = (const float4*)(brec + row0 * RECW);
        float4* dst = (float4*)rec;
        #pragma unroll
        for (int i = 0; i < 3; ++i) dst[i * 256 + tid] = src[i * 256 + tid];
    }

    float st[16];
    #pragma unroll
    for (int n = 0; n < 16; ++n) st[n] = 0.f;
    float cd = 1.f;
    float xh[PFD];
    #pragma unroll
    for (int j = 0; j < PFD; ++j) xh[j] = b2f(xbc[(row0 + j) * 512 + off]);
    __syncthreads();

    for (int s0 = 0; s0 < QCH; s0 += PFD) {
        float xhn[PFD];
        #pragma unroll
        for (int j = 0; j < PFD; ++j)
            xhn[j] = b2f(xbc[(row0 + s0 + PFD + j) * 512 + off]);  // final-batch overread stays in d_ws: safe
        #pragma unroll
        for (int j = 0; j < PFD; ++j) {
            const float* r = rec + (s0 + j) * RECW;
            float da  = r[32 + h];
            float dtt = r[40 + h];
            float xdt = xh[j] * dtt;
            const float4* B4 = (const float4*)r;
            #pragma unroll
            for (int q = 0; q < 4; ++q) {
                float4 Bv = B4[q];
                st[q*4+0] = da * st[q*4+0] + xdt * Bv.x;
                st[q*4+1] = da * st[q*4+1] + xdt * Bv.y;
                st[q*4+2] = da * st[q*4+2] + xdt * Bv.z;
                st[q*4+3] = da * st[q*4+3] + xdt * Bv.w;
            }
            cd *= da;
        }
        #pragma unroll
        for (int j = 0; j < PFD; ++j) xh[j] = xhn[j];
    }
    size_t base = (size_t)((b * 8 + h) * NCH + c) * 1024 + p * 16;
    #pragma unroll
    for (int q = 0; q < 4; ++q)
        *(float4*)&sbuf[base + q * 4] = make_float4(st[q*4], st[q*4+1], st[q*4+2], st[q*4+3]);
    if (p == 0) cdf[(b * 8 + h) * NCH + c] = cd;
}

// ---------------------------------------------------------------
// phase 2: sequential chain over chunks (tiny). block = (h, b); thread holds 4 states.
__global__ void __launch_bounds__(256) k_chain(const float* __restrict__ sbuf,
                                               const float* __restrict__ cdf,
                                               float* __restrict__ hin) {
    int h = blockIdx.x, b = blockIdx.y;
    int tid = threadIdx.x;
    float4 H = make_float4(0.f, 0.f, 0.f, 0.f);
    size_t base = (size_t)((b * 8 + h) * NCH) * 1024;
    for (int c = 0; c < NCH; ++c) {
        *(float4*)&hin[base + (size_t)c * 1024 + tid * 4] = H;
        float cdfv = cdf[(b * 8 + h) * NCH + c];
        float4 S = *(const float4*)&sbuf[base + (size_t)c * 1024 + tid * 4];
        H.x = cdfv * H.x + S.x;
        H.y = cdfv * H.y + S.y;
        H.z = cdfv * H.z + S.z;
        H.w = cdfv * H.w + S.w;
    }
}

// ---------------------------------------------------------------
// scan phase 3: full re-scan from Hin (exact y) + gate -> yg buffer.
// Records in LDS; xh/zz batch-prefetched PFD deep. block = 8 heads x 64 p; grid (NCH, B).
__global__ void __launch_bounds__(512) k_scan2(const ushort_t* __restrict__ xbc,
                                               const ushort_t* __restrict__ z_bf,
                                               const float* __restrict__ brec,
                                               const float* __restrict__ Dp,
                                               const float* __restrict__ hin,
                                               ushort_t* __restrict__ yg_out) {
    __shared__ float rec[QCH * RECW];     // 12 KB
    int c = blockIdx.x, b = blockIdx.y;
    int tid = threadIdx.x;
    int h = tid >> 6, p = tid & 63;
    int off = h * 64 + p;
    size_t row0 = (size_t)b * L_SEQ + (size_t)c * QCH;

    {
        const float4* src = (const float4*)(brec + row0 * RECW);
        float4* dst = (float4*)rec;
        dst[tid] = src[tid];
        if (tid < 256) dst[512 + tid] = src[512 + tid];
    }

    float st[16];
    const float4* H = (const float4*)&hin[(size_t)((b * 8 + h) * NCH + c) * 1024 + p * 16];
    #pragma unroll
    for (int q = 0; q < 4; ++q) {
        float4 Hv = H[q];
        st[q*4+0] = Hv.x; st[q*4+1] = Hv.y; st[q*4+2] = Hv.z; st[q*4+3] = Hv.w;
    }
    float Dh = Dp[h];
    float xh[PFD], zz[PFD];
    #pragma unroll
    for (int j = 0; j < PFD; ++j) {
        xh[j] = b2f(xbc[(row0 + j) * 512 + off]);
        zz[j] = b2f(z_bf[(row0 + j) * 512 + off]);
    }
    __syncthreads();

    for (int s0 = 0; s0 < QCH; s0 += PFD) {
        float xhn[PFD], zzn[PFD];
        #pragma unroll
        for (int j = 0; j < PFD; ++j) {
            size_t rn = row0 + s0 + PFD + j;     // final-batch overread stays in d_ws: safe
            xhn[j] = b2f(xbc[rn * 512 + off]);
            zzn[j] = b2f(z_bf[rn * 512 + off]);
        }
        #pragma unroll
        for (int j = 0; j < PFD; ++j) {
            const float* r = rec + (s0 + j) * RECW;
            float da  = r[32 + h];
            float dtt = r[40 + h];
            float xdt = xh[j] * dtt;
            const float4* B4 = (const float4*)r;
            const float4* C4 = (const float4*)(r + 16);
            float d0 = 0.f, d1 = 0.f, d2 = 0.f, d3 = 0.f;
            #pragma unroll
            for (int q = 0; q < 4; ++q) {
                float4 Bv = B4[q];
                float4 Cv = C4[q];
                st[q*4+0] = da * st[q*4+0] + xdt * Bv.x;
                st[q*4+1] = da * st[q*4+1] + xdt * Bv.y;
                st[q*4+2] = da * st[q*4+2] + xdt * Bv.z;
                st[q*4+3] = da * st[q*4+3] + xdt * Bv.w;
                d0 += st[q*4+0] * Cv.x;
                d1 += st[q*4+1] * Cv.y;
                d2 += st[q*4+2] * Cv.z;
                d3 += st[q*4+3] * Cv.w;
            }
            float y = (d0 + d1) + (d2 + d3) + Dh * xh[j];
            float ygv = y * (zz[j] / (1.f + __expf(-zz[j])));
            yg_out[(row0 + s0 + j) * 512 + off] = f2b(ygv);
        }
        #pragma unroll
        for (int j = 0; j < PFD; ++j) { xh[j] = xhn[j]; zz[j] = zzn[j]; }
    }
}

// ---------------------------------------------------------------
__global__ void __launch_bounds__(256) k_scatter(const ushort_t* __restrict__ tmp,
                                                 const float* __restrict__ ub,
                                                 const float* __restrict__ xin,
                                                 float* __restrict__ out) {
    int tid = threadIdx.x;
    int w = tid & 127;
    int h = (blockIdx.x << 1) | (tid >> 7);
    int c = blockIdx.y >> 3, t = blockIdx.y & 7;
    int b = blockIdx.z;
    size_t row = (size_t)b * L_SEQ + t * 1024 + (h >> 2) * 32 + (w >> 2);
    int kk = c * 16 + (h & 3) * 4 + (w & 3);
    size_t oidx = (((size_t)(b * C_INCH + c) * T_N + t) << 14) + (size_t)h * W_IMG + w;
    out[oidx] = b2f(tmp[row * KPATCH + kk]) + ub[c] + xin[oidx];
}

// ---------------------------------------------------------------
extern "C" void kernel_launch(void* const* d_in, const int* in_sizes, int n_in,
                              void* d_out, int out_size, void* d_ws, size_t ws_size,
                              hipStream_t stream) {
    const float* x       = (const float*)d_in[0];
    const float* patch_w = (const float*)d_in[1];
    const float* patch_b = (const float*)d_in[2];
    const float* W_in    = (const float*)d_in[3];
    const float* conv_w  = (const float*)d_in[4];
    const float* conv_b  = (const float*)d_in[5];
    const float* dt_bias = (const float*)d_in[6];
    const float* A_log   = (const float*)d_in[7];
    const float* D_param = (const float*)d_in[8];
    const float* norm_w  = (const float*)d_in[9];
    const float* W_out   = (const float*)d_in[10];
    const float* unemb_w = (const float*)d_in[11];
    const float* unemb_b = (const float*)d_in[12];
    float* out = (float*)d_out;

    // ---- workspace carve ----
    char* p = (char*)d_ws;
    ushort_t* scratch = (ushort_t*)p; p += (size_t)BLROWS * 384 * 2;   // 25 MB (bf16 tmp)
    float* cdf  = (float*)p;   p += (size_t)32 * NCH * 4;
    float* sbuf = (float*)p;   p += (size_t)32 * NCH * 1024 * 4;       // 16.8 MB
    float* hin  = (float*)p;   p += (size_t)32 * NCH * 1024 * 4;       // 16.8 MB
    float* brec = (float*)p;   p += (size_t)BLROWS * RECW * 4;         // 6.3 MB
    ushort_t* Wt_p   = (ushort_t*)p; p += (size_t)256 * 384 * 2;
    ushort_t* Wt_in  = (ushort_t*)p; p += (size_t)1152 * 256 * 2;
    ushort_t* Wt_out = (ushort_t*)p; p += (size_t)256 * 512 * 2;
    ushort_t* Wt_un  = (ushort_t*)p; p += (size_t)384 * 256 * 2;
    ushort_t* xs     = (ushort_t*)p; p += (size_t)BLROWS * DM_ * 2;    // 16.8 MB
    ushort_t* xbc    = (ushort_t*)p; p += (size_t)BLROWS * 512 * 2;    // 33.5 MB
    ushort_t* z_bf   = (ushort_t*)p; p += (size_t)BLROWS * 512 * 2;    // 33.5 MB
    ushort_t* xbcdt  = (ushort_t*)p; p += (size_t)BLROWS * 640 * 2;    // 41.9 MB (later: yg)
    size_t need = (size_t)(p - (char*)d_ws);
    if (ws_size < need) return;

    ushort_t* tmp = scratch;            // bf16 unembed output
    ushort_t* yg  = xbcdt;              // yg overlays xbcdt (dead after conv)

    k_castpad<<<256, 384, 0, stream>>>(patch_w, Wt_p);
    k_transcast<<<1152, 256, 0, stream>>>(W_in, Wt_in, 256, 1064, nullptr);
    k_transcast<<<256, 256, 0, stream>>>(W_out, Wt_out, 512, 256, norm_w);  // fold RMSNorm weight
    k_transcast<<<384, 256, 0, stream>>>(unemb_w, Wt_un, 256, 368, nullptr);

    // fused im2col + patch GEMM
    k_pgemm<<<dim3(2, 256), 256, 0, stream>>>(x, Wt_p, xs, patch_b);

    // in-proj split: z cols 0..511 -> z_bf; xBC+dt cols 512..1063 -> xbcdt
    k_mgemm<256, 512, true, false><<<dim3(4, 256), 256, 0, stream>>>(xs, 256, Wt_in, z_bf, 512, 0, nullptr);
    k_mgemm<256, 552, true, false><<<dim3(5, 256), 256, 0, stream>>>(xs, 256, Wt_in + (size_t)512 * 256, xbcdt, 640, 0, nullptr);

    k_conv<<<BLROWS / 8, 256, 0, stream>>>(xbcdt, conv_w, conv_b, dt_bias, A_log, xbc, brec);

    k_scan1<<<dim3(NCH, 2, 4), 256, 0, stream>>>(xbc, brec, sbuf, cdf);
    k_chain<<<dim3(8, 4), 256, 0, stream>>>(sbuf, cdf, hin);
    k_scan2<<<dim3(NCH, 4), 512, 0, stream>>>(xbc, z_bf, brec, D_param, hin, yg);

    // out-proj with in-kernel fused RMSNorm (ASCALE): out_seq bf16 -> xs
    k_mgemm<512, 256, true, true><<<dim3(2, 256), 256, 0, stream>>>(yg, 512, Wt_out, xs, DM_, 0, nullptr);

    k_mgemm<256, 368, true, false><<<dim3(3, 256), 256, 0, stream>>>(xs, 256, Wt_un, tmp, KPATCH, 0, nullptr);

    k_scatter<<<dim3(64, 184, 4), 256, 0, stream>>>(tmp, unemb_b, x, out);
}

// Round 13
// 256.602 us; speedup vs baseline: 1.1645x; 1.0119x over previous
//
#include <hip/hip_runtime.h>
#include <hip/hip_bf16.h>
#include <cstdint>
#include <cstddef>

// ---- problem constants ----
#define B_N       4
#define C_INCH    23
#define T_N       8
#define W_IMG     128
#define L_SEQ     8192
#define BLROWS    32768      // B_N * L_SEQ
#define DM_       256
#define D_INNER_  512
#define CONV_DIM_ 544
#define D_PROJ    1064
#define KPATCH    368        // C_INCH*4*4
#define QCH       64         // scan chunk length
#define NCH       128        // chunks per batch
#define RECW      56         // packed scan record (floats): B16 C16 dA8 dt8 ldA8
#define PFD       8          // scan prefetch depth (steps)

typedef unsigned short ushort_t;
typedef unsigned int uint_t;
typedef __attribute__((ext_vector_type(8))) short short8;
typedef __attribute__((ext_vector_type(4))) float f32x4;

__device__ __forceinline__ float b2f(ushort_t u) {
    union { float f; uint_t u; } v; v.u = ((uint_t)u) << 16; return v.f;
}
__device__ __forceinline__ ushort_t f2b(float f) {
    union { float f; uint_t u; } v; v.f = f;
    uint_t r = v.u + 0x7fffu + ((v.u >> 16) & 1u);
    return (ushort_t)(r >> 16);
}

// async global->LDS, 16B per lane. LDS dest = wave-uniform base + lane*16.
__device__ __forceinline__ void gload_lds16(const ushort_t* g, ushort_t* l) {
    __builtin_amdgcn_global_load_lds(
        (const __attribute__((address_space(1))) unsigned int*)g,
        (__attribute__((address_space(3))) unsigned int*)l, 16, 0, 0);
}

// build a bf16 short8 frag from 8 consecutive f32 (or zeros if !live)
__device__ __forceinline__ short8 frag8(const float* q, bool live) {
    short8 f;
    if (live) {
        float4 lo = *(const float4*)q, hi = *(const float4*)(q + 4);
        f[0] = (short)f2b(lo.x); f[1] = (short)f2b(lo.y);
        f[2] = (short)f2b(lo.z); f[3] = (short)f2b(lo.w);
        f[4] = (short)f2b(hi.x); f[5] = (short)f2b(hi.y);
        f[6] = (short)f2b(hi.z); f[7] = (short)f2b(hi.w);
    } else {
        #pragma unroll
        for (int e = 0; e < 8; ++e) f[e] = 0;
    }
    return f;
}

// ---------------------------------------------------------------
// weight prep: dst[Npad][K] bf16 = transpose(src[K][N] fp32) * (rscale?rscale[k]:1)
__global__ void k_transcast(const float* __restrict__ src, ushort_t* __restrict__ dst,
                            int K, int N, const float* __restrict__ rscale) {
    int n = blockIdx.x;
    for (int k = threadIdx.x; k < K; k += 256) {
        float v = 0.f;
        if (n < N) {
            v = src[(size_t)k * N + n];
            if (rscale) v *= rscale[k];
        }
        dst[(size_t)n * K + k] = f2b(v);
    }
}

// patch weights are already [d][k]: direct cast + pad k to 384
__global__ void k_castpad(const float* __restrict__ src, ushort_t* __restrict__ dst) {
    int d = blockIdx.x; int k = threadIdx.x;   // 384 threads
    dst[d * 384 + k] = (k < KPATCH) ? f2b(src[d * KPATCH + k]) : (ushort_t)0;
}

// ---------------------------------------------------------------
// fused patch-embed GEMM: xs[BL,256] = gather-im2col(x)[BL,384] @ Wt_p[256][384] + pb.
__global__ void __launch_bounds__(256) k_pgemm(const float* __restrict__ x,
                                               const ushort_t* __restrict__ Wt,
                                               ushort_t* __restrict__ Cv,
                                               const float* __restrict__ bias) {
    __shared__ ushort_t Al[128 * 64];
    __shared__ ushort_t Bl[128 * 64];
    const int tid = threadIdx.x;
    const int w = tid >> 6, lane = tid & 63;
    const int wr = w >> 1, wc = w & 1;
    const int rowbase = blockIdx.y * 128;
    const int colbase = blockIdx.x * 128;
    const int g = lane >> 4, r = lane & 15;
    const int b  = rowbase >> 13;
    const int t  = (rowbase >> 10) & 7;
    const int hp0 = (rowbase >> 5) & 31;

    f32x4 acc[4][4];
    #pragma unroll
    for (int i = 0; i < 4; ++i)
        #pragma unroll
        for (int j = 0; j < 4; ++j) acc[i][j] = (f32x4){0.f, 0.f, 0.f, 0.f};

    for (int it = 0; it < 6; ++it) {        // K=384, BK=64
        int k0 = it * 64;
        __syncthreads();
        #pragma unroll
        for (int i2 = 0; i2 < 4; ++i2) {
            int s = i2 * 256 + (w << 6) + lane;
            int row = s >> 3;
            int c16 = (s & 7) ^ (row & 7);
            gload_lds16(Wt + (size_t)(colbase + row) * 384 + k0 + c16 * 8,
                        &Bl[(size_t)(i2 * 256 + (w << 6)) * 8]);
        }
        #pragma unroll
        for (int i2 = 0; i2 < 8; ++i2) {
            int idx = i2 * 256 + tid;
            int row = idx >> 4, kq = idx & 15;
            int c = (k0 >> 4) + (kq >> 2);
            int i = kq & 3;
            uint_t u0 = 0, u1 = 0;
            if (c < C_INCH) {
                int hp = hp0 + (row >> 5), wp = row & 31;
                const float4 v = *(const float4*)&x[(((size_t)(b * C_INCH + c) * T_N + t) << 14)
                                                    + (size_t)(hp * 4 + i) * W_IMG + wp * 4];
                u0 = (uint_t)f2b(v.x) | ((uint_t)f2b(v.y) << 16);
                u1 = (uint_t)f2b(v.z) | ((uint_t)f2b(v.w) << 16);
            }
            int slot = (row << 3) + ((kq >> 1) ^ (row & 7));
            *(uint2*)&Al[(size_t)slot * 8 + (kq & 1) * 4] = make_uint2(u0, u1);
        }
        __syncthreads();

        short8 af[2][4], bf[2][4];
        #pragma unroll
        for (int ks = 0; ks < 2; ++ks)
            #pragma unroll
            for (int mi = 0; mi < 4; ++mi) {
                int row = (wr << 6) + (mi << 4) + r;
                int c16 = ((ks << 2) | g) ^ (row & 7);
                af[ks][mi] = *(const short8*)&Al[(size_t)((row << 3) + c16) * 8];
            }
        #pragma unroll
        for (int ks = 0; ks < 2; ++ks)
            #pragma unroll
            for (int ni = 0; ni < 4; ++ni) {
                int row = (wc << 6) + (ni << 4) + r;
                int c16 = ((ks << 2) | g) ^ (row & 7);
                bf[ks][ni] = *(const short8*)&Bl[(size_t)((row << 3) + c16) * 8];
            }
        #pragma unroll
        for (int ks = 0; ks < 2; ++ks)
            #pragma unroll
            for (int mi = 0; mi < 4; ++mi)
                #pragma unroll
                for (int ni = 0; ni < 4; ++ni)
                    acc[mi][ni] = __builtin_amdgcn_mfma_f32_16x16x32_bf16(
                        af[ks][mi], bf[ks][ni], acc[mi][ni], 0, 0, 0);
    }

    #pragma unroll
    for (int mi = 0; mi < 4; ++mi) {
        int rw = rowbase + (wr << 6) + (mi << 4) + (g << 2);
        #pragma unroll
        for (int ni = 0; ni < 4; ++ni) {
            int col = colbase + (wc << 6) + (ni << 4) + r;
            float bv = bias[col];
            f32x4 v = acc[mi][ni];
            #pragma unroll
            for (int j = 0; j < 4; ++j)
                Cv[(size_t)(rw + j) * DM_ + col] = f2b(v[j] + bv);
        }
    }
}

// ---------------------------------------------------------------
// MFMA GEMM with optional fused RMSNorm row-scale (ASCALE).
template <int K, int N, bool CBF, bool ASCALE>
__global__ void __launch_bounds__(256) k_mgemm(const ushort_t* __restrict__ A, const int lda,
                                               const ushort_t* __restrict__ Wt,
                                               void* __restrict__ Cv, const int ldc, const int coff,
                                               const float* __restrict__ bias) {
    __shared__ ushort_t Al[128 * 64];
    __shared__ ushort_t Bl[128 * 64];
    const int tid = threadIdx.x;
    const int w = tid >> 6, lane = tid & 63;
    const int wr = w >> 1, wc = w & 1;
    const int rowbase = blockIdx.y * 128;
    const int colbase = blockIdx.x * 128;
    const int g = lane >> 4, r = lane & 15;

    f32x4 acc[4][4];
    #pragma unroll
    for (int i = 0; i < 4; ++i)
        #pragma unroll
        for (int j = 0; j < 4; ++j) acc[i][j] = (f32x4){0.f, 0.f, 0.f, 0.f};
    float rs[4] = {0.f, 0.f, 0.f, 0.f};

    for (int k0 = 0; k0 < K; k0 += 64) {
        __syncthreads();
        #pragma unroll
        for (int it = 0; it < 4; ++it) {
            int s = it * 256 + (w << 6) + lane;
            int row = s >> 3;
            int c16 = (s & 7) ^ (row & 7);
            gload_lds16(A + (size_t)(rowbase + row) * lda + k0 + c16 * 8,
                        &Al[(size_t)(it * 256 + (w << 6)) * 8]);
        }
        #pragma unroll
        for (int it = 0; it < 4; ++it) {
            int s = it * 256 + (w << 6) + lane;
            int row = s >> 3;
            int c16 = (s & 7) ^ (row & 7);
            gload_lds16(Wt + (size_t)(colbase + row) * K + k0 + c16 * 8,
                        &Bl[(size_t)(it * 256 + (w << 6)) * 8]);
        }
        __syncthreads();

        short8 af[2][4], bf[2][4];
        #pragma unroll
        for (int ks = 0; ks < 2; ++ks)
            #pragma unroll
            for (int mi = 0; mi < 4; ++mi) {
                int row = (wr << 6) + (mi << 4) + r;
                int c16 = ((ks << 2) | g) ^ (row & 7);
                af[ks][mi] = *(const short8*)&Al[(size_t)((row << 3) + c16) * 8];
            }
        #pragma unroll
        for (int ks = 0; ks < 2; ++ks)
            #pragma unroll
            for (int ni = 0; ni < 4; ++ni) {
                int row = (wc << 6) + (ni << 4) + r;
                int c16 = ((ks << 2) | g) ^ (row & 7);
                bf[ks][ni] = *(const short8*)&Bl[(size_t)((row << 3) + c16) * 8];
            }
        if (ASCALE) {
            #pragma unroll
            for (int ks = 0; ks < 2; ++ks)
                #pragma unroll
                for (int mi = 0; mi < 4; ++mi)
                    #pragma unroll
                    for (int e = 0; e < 8; ++e) {
                        float v = b2f((ushort_t)af[ks][mi][e]);
                        rs[mi] += v * v;
                    }
        }
        #pragma unroll
        for (int ks = 0; ks < 2; ++ks)
            #pragma unroll
            for (int mi = 0; mi < 4; ++mi)
                #pragma unroll
                for (int ni = 0; ni < 4; ++ni)
                    acc[mi][ni] = __builtin_amdgcn_mfma_f32_16x16x32_bf16(
                        af[ks][mi], bf[ks][ni], acc[mi][ni], 0, 0, 0);
    }

    #pragma unroll
    for (int mi = 0; mi < 4; ++mi) {
        int rw = rowbase + (wr << 6) + (mi << 4) + (g << 2);
        float sj[4] = {1.f, 1.f, 1.f, 1.f};
        if (ASCALE) {
            float s = rs[mi];
            s += __shfl_xor(s, 16);
            s += __shfl_xor(s, 32);
            float sc = rsqrtf(s * (1.f / 512.f) + 1e-5f);
            #pragma unroll
            for (int j = 0; j < 4; ++j) sj[j] = __shfl(sc, 4 * g + j);
        }
        #pragma unroll
        for (int ni = 0; ni < 4; ++ni) {
            int col = colbase + (wc << 6) + (ni << 4) + r;
            if (col < N) {
                float bv = bias ? bias[col] : 0.f;
                f32x4 v = acc[mi][ni];
                #pragma unroll
                for (int j = 0; j < 4; ++j) {
                    size_t cidx = (size_t)(rw + j) * ldc + coff + col;
                    float vr = v[j] * sj[j] + bv;
                    if (CBF) ((ushort_t*)Cv)[cidx] = f2b(vr);
                    else     ((float*)Cv)[cidx]   = vr;
                }
            }
        }
    }
}

// ---------------------------------------------------------------
// causal depthwise conv + silu; brec: B[0..15] C[16..31] dA[32..39] dt[40..47] ldA[48..55]
__global__ void __launch_bounds__(256) k_conv(const ushort_t* __restrict__ xbcdt,
                                              const float* __restrict__ cw,
                                              const float* __restrict__ cb,
                                              const float* __restrict__ dtb,
                                              const float* __restrict__ alog,
                                              ushort_t* __restrict__ xbc,
                                              float* __restrict__ brec) {
    int tid = threadIdx.x;
    int rb = blockIdx.x * 8;
    int srb = rb & (L_SEQ - 1);
    #pragma unroll
    for (int it = 0; it < 3; ++it) {
        int ch = it * 256 + tid;
        if (ch >= 552) break;
        if (ch < CONV_DIM_) {
            float w0 = cw[ch * 4 + 0], w1 = cw[ch * 4 + 1];
            float w2 = cw[ch * 4 + 2], w3 = cw[ch * 4 + 3];
            float bias = cb[ch];
            float win[11];
            #pragma unroll
            for (int j = 0; j < 11; ++j) {
                int sj = srb + j - 3;
                win[j] = (sj >= 0) ? b2f(xbcdt[(size_t)(rb + j - 3) * 640 + ch]) : 0.f;
            }
            #pragma unroll
            for (int r = 0; r < 8; ++r) {
                float acc = bias + win[r] * w0 + win[r + 1] * w1 + win[r + 2] * w2 + win[r + 3] * w3;
                float s = acc / (1.f + __expf(-acc));
                size_t row = rb + r;
                if (ch < 512) xbc[row * 512 + ch] = f2b(s);
                else          brec[row * RECW + (ch - 512)] = s;
            }
        } else {
            int h = ch - CONV_DIM_;
            float A = -__expf(alog[h]);
            float db = dtb[h];
            #pragma unroll
            for (int r = 0; r < 8; ++r) {
                size_t row = rb + r;
                float v = b2f(xbcdt[row * 640 + ch]) + db;
                float sp = (v > 20.f) ? v : log1pf(__expf(v));
                brec[row * RECW + 32 + h] = __expf(sp * A);   // dA
                brec[row * RECW + 40 + h] = sp;               // dt
                brec[row * RECW + 48 + h] = sp * A;           // ldA (log decay)
            }
        }
    }
}

// ---------------------------------------------------------------
// scan phase 1 (scalar, unchanged logic): chunk-final states + per-chunk decay.
__global__ void __launch_bounds__(256) k_scan1(const ushort_t* __restrict__ xbc,
                                               const float* __restrict__ brec,
                                               float* __restrict__ sbuf,
                                               float* __restrict__ cdf) {
    __shared__ float rec[QCH * RECW];     // 14 KB
    int c = blockIdx.x, b = blockIdx.z;
    int tid = threadIdx.x;
    int h = blockIdx.y * 4 + (tid >> 6);
    int p = tid & 63;
    int off = h * 64 + p;
    size_t row0 = (size_t)b * L_SEQ + (size_t)c * QCH;

    {
        const float4* src = (const float4*)(brec + row0 * RECW);
        float4* dst = (float4*)rec;
        #pragma unroll
        for (int i = 0; i < 3; ++i) dst[i * 256 + tid] = src[i * 256 + tid];
        if (tid < 128) dst[768 + tid] = src[768 + tid];
    }

    float st[16];
    #pragma unroll
    for (int n = 0; n < 16; ++n) st[n] = 0.f;
    float cd = 1.f;
    float xh[PFD];
    #pragma unroll
    for (int j = 0; j < PFD; ++j) xh[j] = b2f(xbc[(row0 + j) * 512 + off]);
    __syncthreads();

    for (int s0 = 0; s0 < QCH; s0 += PFD) {
        float xhn[PFD];
        #pragma unroll
        for (int j = 0; j < PFD; ++j)
            xhn[j] = b2f(xbc[(row0 + s0 + PFD + j) * 512 + off]);  // overread stays in d_ws: safe
        #pragma unroll
        for (int j = 0; j < PFD; ++j) {
            const float* r = rec + (s0 + j) * RECW;
            float da  = r[32 + h];
            float dtt = r[40 + h];
            float xdt = xh[j] * dtt;
            const float4* B4 = (const float4*)r;
            #pragma unroll
            for (int q = 0; q < 4; ++q) {
                float4 Bv = B4[q];
                st[q*4+0] = da * st[q*4+0] + xdt * Bv.x;
                st[q*4+1] = da * st[q*4+1] + xdt * Bv.y;
                st[q*4+2] = da * st[q*4+2] + xdt * Bv.z;
                st[q*4+3] = da * st[q*4+3] + xdt * Bv.w;
            }
            cd *= da;
        }
        #pragma unroll
        for (int j = 0; j < PFD; ++j) xh[j] = xhn[j];
    }
    size_t base = (size_t)((b * 8 + h) * NCH + c) * 1024 + p * 16;
    #pragma unroll
    for (int q = 0; q < 4; ++q)
        *(float4*)&sbuf[base + q * 4] = make_float4(st[q*4], st[q*4+1], st[q*4+2], st[q*4+3]);
    if (p == 0) cdf[(b * 8 + h) * NCH + c] = cd;
}

// ---------------------------------------------------------------
// phase 2: sequential chain over chunks (tiny).
__global__ void __launch_bounds__(256) k_chain(const float* __restrict__ sbuf,
                                               const float* __restrict__ cdf,
                                               float* __restrict__ hin) {
    int h = blockIdx.x, b = blockIdx.y;
    int tid = threadIdx.x;
    float4 H = make_float4(0.f, 0.f, 0.f, 0.f);
    size_t base = (size_t)((b * 8 + h) * NCH) * 1024;
    for (int c = 0; c < NCH; ++c) {
        *(float4*)&hin[base + (size_t)c * 1024 + tid * 4] = H;
        float cdfv = cdf[(b * 8 + h) * NCH + c];
        float4 S = *(const float4*)&sbuf[base + (size_t)c * 1024 + tid * 4];
        H.x = cdfv * H.x + S.x;
        H.y = cdfv * H.y + S.y;
        H.z = cdfv * H.z + S.z;
        H.w = cdfv * H.w + S.w;
    }
}

// ---------------------------------------------------------------
// SSD scan phase 3 via MFMA: per (b,h,c) one wave.
// Y = P @ Xh + diag(exp S)·(C @ Hin), P[i][j] = (C_i·B_j)·exp(S_i-S_j)·dt_j (j<=i).
// Then y += D*xh, gate with silu(z), write yg (bf16).
__global__ void __launch_bounds__(64) k_ssc2(const ushort_t* __restrict__ xbc,
                                             const ushort_t* __restrict__ z_bf,
                                             const float* __restrict__ brec,
                                             const float* __restrict__ Dp,
                                             const float* __restrict__ hin,
                                             ushort_t* __restrict__ yg_out) {
    __shared__ ushort_t XhT[64 * 72];   // [p][j] bf16, padded rows (144B)
    __shared__ ushort_t Pl [64 * 72];   // [i][j] bf16, padded rows
    __shared__ float Sl[64], Tl[64], El[64];
    const int c = blockIdx.x, h = blockIdx.y, b = blockIdx.z;
    const int lane = threadIdx.x;
    const int g = lane >> 4, r = lane & 15;
    const size_t row0 = (size_t)b * L_SEQ + (size_t)c * QCH;
    const size_t bhc = (size_t)(b * 8 + h) * NCH + c;

    // ---- load own row's xh (64 bf16) and prefix quantities
    uint4 xw[8];
    {
        const uint4* xsrc = (const uint4*)(xbc + (row0 + lane) * 512 + h * 64);
        #pragma unroll
        for (int q = 0; q < 8; ++q) xw[q] = xsrc[q];
    }
    float ldA = brec[(row0 + lane) * RECW + 48 + h];
    float dtv = brec[(row0 + lane) * RECW + 40 + h];

    // Kogge-Stone inclusive prefix of ldA over 64 lanes
    float S = ldA;
    #pragma unroll
    for (int d = 1; d < 64; d <<= 1) {
        float o = __shfl(S, (lane >= d) ? (lane - d) : 0);
        if (lane >= d) S += o;
    }
    Sl[lane] = S;
    Tl[lane] = S - __logf(dtv);
    El[lane] = __expf(S);

    // transpose xh row into XhT[p][lane]
    #pragma unroll
    for (int p = 0; p < 64; ++p) {
        uint4 v = xw[p >> 3];
        int sub = (p >> 1) & 3;
        uint_t word = (sub == 0) ? v.x : (sub == 1) ? v.y : (sub == 2) ? v.z : v.w;
        XhT[p * 72 + lane] = (ushort_t)((p & 1) ? (word >> 16) : (word & 0xffffu));
    }

    // C/B fragments straight from brec (f32 -> bf16), K padded 16->32 (g>=2 zero)
    short8 cwf[4], bwf[4];
    #pragma unroll
    for (int t4 = 0; t4 < 4; ++t4) {
        cwf[t4] = frag8(brec + (row0 + t4 * 16 + r) * RECW + 16 + g * 8, g < 2);
        bwf[t4] = frag8(brec + (row0 + t4 * 16 + r) * RECW + 0  + g * 8, g < 2);
    }
    __syncthreads();

    // ---- MFMA-1: M^T[j][i] = sum_n B[j][n] C[i][n]; mask -> P (bf16 in LDS)
    #pragma unroll
    for (int j0t = 0; j0t < 4; ++j0t) {
        #pragma unroll
        for (int i0t = 0; i0t < 4; ++i0t) {
            f32x4 m = (f32x4){0.f, 0.f, 0.f, 0.f};
            m = __builtin_amdgcn_mfma_f32_16x16x32_bf16(bwf[j0t], cwf[i0t], m, 0, 0, 0);
            // D: col=lane&15 -> i, row=g*4+reg -> j
            int i = i0t * 16 + r;
            float si = Sl[i];
            float4 tj = *(const float4*)&Tl[j0t * 16 + g * 4];
            ushort_t pv[4];
            #pragma unroll
            for (int reg = 0; reg < 4; ++reg) {
                int j = j0t * 16 + g * 4 + reg;
                float tjv = (reg == 0) ? tj.x : (reg == 1) ? tj.y : (reg == 2) ? tj.z : tj.w;
                float mask = (j <= i) ? __expf(si - tjv) : 0.f;
                pv[reg] = f2b(m[reg] * mask);
            }
            uint2 packed = make_uint2((uint_t)pv[0] | ((uint_t)pv[1] << 16),
                                      (uint_t)pv[2] | ((uint_t)pv[3] << 16));
            *(uint2*)&Pl[i * 72 + j0t * 16 + g * 4] = packed;
        }
    }
    __syncthreads();

    // ---- hoist Xh B-frags and Hin boundary B-frags
    short8 xhf[4][2];
    #pragma unroll
    for (int p0t = 0; p0t < 4; ++p0t)
        #pragma unroll
        for (int kk = 0; kk < 2; ++kk)
            xhf[p0t][kk] = *(const short8*)&XhT[(p0t * 16 + r) * 72 + kk * 32 + g * 8];
    short8 hinf[4];
    #pragma unroll
    for (int p0t = 0; p0t < 4; ++p0t)
        hinf[p0t] = frag8(hin + bhc * 1024 + (size_t)(p0t * 16 + r) * 16 + g * 8, g < 2);

    const float Dh = Dp[h];

    // ---- per output tile: boundary MFMA, scale by exp(S_i), P@Xh, epilogue
    #pragma unroll
    for (int i0t = 0; i0t < 4; ++i0t) {
        short8 pa0 = *(const short8*)&Pl[(i0t * 16 + r) * 72 + 0  + g * 8];
        short8 pa1 = *(const short8*)&Pl[(i0t * 16 + r) * 72 + 32 + g * 8];
        float4 e4 = *(const float4*)&El[i0t * 16 + g * 4];
        #pragma unroll
        for (int p0t = 0; p0t < 4; ++p0t) {
            f32x4 acc = (f32x4){0.f, 0.f, 0.f, 0.f};
            acc = __builtin_amdgcn_mfma_f32_16x16x32_bf16(cwf[i0t], hinf[p0t], acc, 0, 0, 0);
            acc[0] *= e4.x; acc[1] *= e4.y; acc[2] *= e4.z; acc[3] *= e4.w;
            acc = __builtin_amdgcn_mfma_f32_16x16x32_bf16(pa0, xhf[p0t][0], acc, 0, 0, 0);
            acc = __builtin_amdgcn_mfma_f32_16x16x32_bf16(pa1, xhf[p0t][1], acc, 0, 0, 0);
            int p = p0t * 16 + r;
            #pragma unroll
            for (int reg = 0; reg < 4; ++reg) {
                int i = i0t * 16 + g * 4 + reg;
                size_t row = row0 + i;
                float xhv = b2f(XhT[p * 72 + i]);
                float y = acc[reg] + Dh * xhv;
                float zz = b2f(z_bf[row * 512 + h * 64 + p]);
                float ygv = y * (zz / (1.f + __expf(-zz)));
                yg_out[row * 512 + h * 64 + p] = f2b(ygv);
            }
        }
    }
}

// ---------------------------------------------------------------
__global__ void __launch_bounds__(256) k_scatter(const ushort_t* __restrict__ tmp,
                                                 const float* __restrict__ ub,
                                                 const float* __restrict__ xin,
                                                 float* __restrict__ out) {
    int tid = threadIdx.x;
    int w = tid & 127;
    int h = (blockIdx.x << 1) | (tid >> 7);
    int c = blockIdx.y >> 3, t = blockIdx.y & 7;
    int b = blockIdx.z;
    size_t row = (size_t)b * L_SEQ + t * 1024 + (h >> 2) * 32 + (w >> 2);
    int kk = c * 16 + (h & 3) * 4 + (w & 3);
    size_t oidx = (((size_t)(b * C_INCH + c) * T_N + t) << 14) + (size_t)h * W_IMG + w;
    out[oidx] = b2f(tmp[row * KPATCH + kk]) + ub[c] + xin[oidx];
}

// ---------------------------------------------------------------
extern "C" void kernel_launch(void* const* d_in, const int* in_sizes, int n_in,
                              void* d_out, int out_size, void* d_ws, size_t ws_size,
                              hipStream_t stream) {
    const float* x       = (const float*)d_in[0];
    const float* patch_w = (const float*)d_in[1];
    const float* patch_b = (const float*)d_in[2];
    const float* W_in    = (const float*)d_in[3];
    const float* conv_w  = (const float*)d_in[4];
    const float* conv_b  = (const float*)d_in[5];
    const float* dt_bias = (const float*)d_in[6];
    const float* A_log   = (const float*)d_in[7];
    const float* D_param = (const float*)d_in[8];
    const float* norm_w  = (const float*)d_in[9];
    const float* W_out   = (const float*)d_in[10];
    const float* unemb_w = (const float*)d_in[11];
    const float* unemb_b = (const float*)d_in[12];
    float* out = (float*)d_out;

    // ---- workspace carve ----
    char* p = (char*)d_ws;
    ushort_t* scratch = (ushort_t*)p; p += (size_t)BLROWS * 384 * 2;   // 25 MB (bf16 tmp)
    float* cdf  = (float*)p;   p += (size_t)32 * NCH * 4;
    float* sbuf = (float*)p;   p += (size_t)32 * NCH * 1024 * 4;       // 16.8 MB
    float* hin  = (float*)p;   p += (size_t)32 * NCH * 1024 * 4;       // 16.8 MB
    float* brec = (float*)p;   p += (size_t)BLROWS * RECW * 4;         // 7.3 MB
    ushort_t* Wt_p   = (ushort_t*)p; p += (size_t)256 * 384 * 2;
    ushort_t* Wt_in  = (ushort_t*)p; p += (size_t)1152 * 256 * 2;
    ushort_t* Wt_out = (ushort_t*)p; p += (size_t)256 * 512 * 2;
    ushort_t* Wt_un  = (ushort_t*)p; p += (size_t)384 * 256 * 2;
    ushort_t* xs     = (ushort_t*)p; p += (size_t)BLROWS * DM_ * 2;    // 16.8 MB
    ushort_t* xbc    = (ushort_t*)p; p += (size_t)BLROWS * 512 * 2;    // 33.5 MB
    ushort_t* z_bf   = (ushort_t*)p; p += (size_t)BLROWS * 512 * 2;    // 33.5 MB
    ushort_t* xbcdt  = (ushort_t*)p; p += (size_t)BLROWS * 640 * 2;    // 41.9 MB (later: yg)
    size_t need = (size_t)(p - (char*)d_ws);
    if (ws_size < need) return;

    ushort_t* tmp = scratch;            // bf16 unembed output
    ushort_t* yg  = xbcdt;              // yg overlays xbcdt (dead after conv)

    k_castpad<<<256, 384, 0, stream>>>(patch_w, Wt_p);
    k_transcast<<<1152, 256, 0, stream>>>(W_in, Wt_in, 256, 1064, nullptr);
    k_transcast<<<256, 256, 0, stream>>>(W_out, Wt_out, 512, 256, norm_w);  // fold RMSNorm weight
    k_transcast<<<384, 256, 0, stream>>>(unemb_w, Wt_un, 256, 368, nullptr);

    // fused im2col + patch GEMM
    k_pgemm<<<dim3(2, 256), 256, 0, stream>>>(x, Wt_p, xs, patch_b);

    // in-proj split: z cols 0..511 -> z_bf; xBC+dt cols 512..1063 -> xbcdt
    k_mgemm<256, 512, true, false><<<dim3(4, 256), 256, 0, stream>>>(xs, 256, Wt_in, z_bf, 512, 0, nullptr);
    k_mgemm<256, 552, true, false><<<dim3(5, 256), 256, 0, stream>>>(xs, 256, Wt_in + (size_t)512 * 256, xbcdt, 640, 0, nullptr);

    k_conv<<<BLROWS / 8, 256, 0, stream>>>(xbcdt, conv_w, conv_b, dt_bias, A_log, xbc, brec);

    k_scan1<<<dim3(NCH, 2, 4), 256, 0, stream>>>(xbc, brec, sbuf, cdf);
    k_chain<<<dim3(8, 4), 256, 0, stream>>>(sbuf, cdf, hin);
    k_ssc2<<<dim3(NCH, 8, 4), 64, 0, stream>>>(xbc, z_bf, brec, D_param, hin, yg);

    // out-proj with in-kernel fused RMSNorm (ASCALE): out_seq bf16 -> xs
    k_mgemm<512, 256, true, true><<<dim3(2, 256), 256, 0, stream>>>(yg, 512, Wt_out, xs, DM_, 0, nullptr);

    k_mgemm<256, 368, true, false><<<dim3(3, 256), 256, 0, stream>>>(xs, 256, Wt_un, tmp, KPATCH, 0, nullptr);

    k_scatter<<<dim3(64, 184, 4), 256, 0, stream>>>(tmp, unemb_b, x, out);
}

// Round 14
// 250.338 us; speedup vs baseline: 1.1936x; 1.0250x over previous
//
#include <hip/hip_runtime.h>
#include <hip/hip_bf16.h>
#include <cstdint>
#include <cstddef>

// ---- problem constants ----
#define B_N       4
#define C_INCH    23
#define T_N       8
#define W_IMG     128
#define L_SEQ     8192
#define BLROWS    32768      // B_N * L_SEQ
#define DM_       256
#define D_INNER_  512
#define CONV_DIM_ 544
#define D_PROJ    1064
#define KPATCH    368        // C_INCH*4*4
#define QCH       64         // scan chunk length
#define NCH       128        // chunks per batch
#define RECW      56         // packed scan record (floats): B16 C16 dA8 dt8 ldA8

typedef unsigned short ushort_t;
typedef unsigned int uint_t;
typedef __attribute__((ext_vector_type(8))) short short8;
typedef __attribute__((ext_vector_type(4))) float f32x4;

__device__ __forceinline__ float b2f(ushort_t u) {
    union { float f; uint_t u; } v; v.u = ((uint_t)u) << 16; return v.f;
}
__device__ __forceinline__ ushort_t f2b(float f) {
    union { float f; uint_t u; } v; v.f = f;
    uint_t r = v.u + 0x7fffu + ((v.u >> 16) & 1u);
    return (ushort_t)(r >> 16);
}

// async global->LDS, 16B per lane. LDS dest = wave-uniform base + lane*16.
__device__ __forceinline__ void gload_lds16(const ushort_t* g, ushort_t* l) {
    __builtin_amdgcn_global_load_lds(
        (const __attribute__((address_space(1))) unsigned int*)g,
        (__attribute__((address_space(3))) unsigned int*)l, 16, 0, 0);
}

// build a bf16 short8 frag from 8 consecutive f32 (or zeros if !live)
__device__ __forceinline__ short8 frag8(const float* q, bool live) {
    short8 f;
    if (live) {
        float4 lo = *(const float4*)q, hi = *(const float4*)(q + 4);
        f[0] = (short)f2b(lo.x); f[1] = (short)f2b(lo.y);
        f[2] = (short)f2b(lo.z); f[3] = (short)f2b(lo.w);
        f[4] = (short)f2b(hi.x); f[5] = (short)f2b(hi.y);
        f[6] = (short)f2b(hi.z); f[7] = (short)f2b(hi.w);
    } else {
        #pragma unroll
        for (int e = 0; e < 8; ++e) f[e] = 0;
    }
    return f;
}

// ---------------------------------------------------------------
// weight prep: dst[Npad][K] bf16 = transpose(src[K][N] fp32) * (rscale?rscale[k]:1)
__global__ void k_transcast(const float* __restrict__ src, ushort_t* __restrict__ dst,
                            int K, int N, const float* __restrict__ rscale) {
    int n = blockIdx.x;
    for (int k = threadIdx.x; k < K; k += 256) {
        float v = 0.f;
        if (n < N) {
            v = src[(size_t)k * N + n];
            if (rscale) v *= rscale[k];
        }
        dst[(size_t)n * K + k] = f2b(v);
    }
}

// patch weights are already [d][k]: direct cast + pad k to 384
__global__ void k_castpad(const float* __restrict__ src, ushort_t* __restrict__ dst) {
    int d = blockIdx.x; int k = threadIdx.x;   // 384 threads
    dst[d * 384 + k] = (k < KPATCH) ? f2b(src[d * KPATCH + k]) : (ushort_t)0;
}

// ---------------------------------------------------------------
// fused patch-embed GEMM: xs[BL,256] = gather-im2col(x)[BL,384] @ Wt_p[256][384] + pb.
__global__ void __launch_bounds__(256) k_pgemm(const float* __restrict__ x,
                                               const ushort_t* __restrict__ Wt,
                                               ushort_t* __restrict__ Cv,
                                               const float* __restrict__ bias) {
    __shared__ ushort_t Al[128 * 64];
    __shared__ ushort_t Bl[128 * 64];
    const int tid = threadIdx.x;
    const int w = tid >> 6, lane = tid & 63;
    const int wr = w >> 1, wc = w & 1;
    const int rowbase = blockIdx.y * 128;
    const int colbase = blockIdx.x * 128;
    const int g = lane >> 4, r = lane & 15;
    const int b  = rowbase >> 13;
    const int t  = (rowbase >> 10) & 7;
    const int hp0 = (rowbase >> 5) & 31;

    f32x4 acc[4][4];
    #pragma unroll
    for (int i = 0; i < 4; ++i)
        #pragma unroll
        for (int j = 0; j < 4; ++j) acc[i][j] = (f32x4){0.f, 0.f, 0.f, 0.f};

    for (int it = 0; it < 6; ++it) {        // K=384, BK=64
        int k0 = it * 64;
        __syncthreads();
        #pragma unroll
        for (int i2 = 0; i2 < 4; ++i2) {
            int s = i2 * 256 + (w << 6) + lane;
            int row = s >> 3;
            int c16 = (s & 7) ^ (row & 7);
            gload_lds16(Wt + (size_t)(colbase + row) * 384 + k0 + c16 * 8,
                        &Bl[(size_t)(i2 * 256 + (w << 6)) * 8]);
        }
        #pragma unroll
        for (int i2 = 0; i2 < 8; ++i2) {
            int idx = i2 * 256 + tid;
            int row = idx >> 4, kq = idx & 15;
            int c = (k0 >> 4) + (kq >> 2);
            int i = kq & 3;
            uint_t u0 = 0, u1 = 0;
            if (c < C_INCH) {
                int hp = hp0 + (row >> 5), wp = row & 31;
                const float4 v = *(const float4*)&x[(((size_t)(b * C_INCH + c) * T_N + t) << 14)
                                                    + (size_t)(hp * 4 + i) * W_IMG + wp * 4];
                u0 = (uint_t)f2b(v.x) | ((uint_t)f2b(v.y) << 16);
                u1 = (uint_t)f2b(v.z) | ((uint_t)f2b(v.w) << 16);
            }
            int slot = (row << 3) + ((kq >> 1) ^ (row & 7));
            *(uint2*)&Al[(size_t)slot * 8 + (kq & 1) * 4] = make_uint2(u0, u1);
        }
        __syncthreads();

        short8 af[2][4], bf[2][4];
        #pragma unroll
        for (int ks = 0; ks < 2; ++ks)
            #pragma unroll
            for (int mi = 0; mi < 4; ++mi) {
                int row = (wr << 6) + (mi << 4) + r;
                int c16 = ((ks << 2) | g) ^ (row & 7);
                af[ks][mi] = *(const short8*)&Al[(size_t)((row << 3) + c16) * 8];
            }
        #pragma unroll
        for (int ks = 0; ks < 2; ++ks)
            #pragma unroll
            for (int ni = 0; ni < 4; ++ni) {
                int row = (wc << 6) + (ni << 4) + r;
                int c16 = ((ks << 2) | g) ^ (row & 7);
                bf[ks][ni] = *(const short8*)&Bl[(size_t)((row << 3) + c16) * 8];
            }
        #pragma unroll
        for (int ks = 0; ks < 2; ++ks)
            #pragma unroll
            for (int mi = 0; mi < 4; ++mi)
                #pragma unroll
                for (int ni = 0; ni < 4; ++ni)
                    acc[mi][ni] = __builtin_amdgcn_mfma_f32_16x16x32_bf16(
                        af[ks][mi], bf[ks][ni], acc[mi][ni], 0, 0, 0);
    }

    #pragma unroll
    for (int mi = 0; mi < 4; ++mi) {
        int rw = rowbase + (wr << 6) + (mi << 4) + (g << 2);
        #pragma unroll
        for (int ni = 0; ni < 4; ++ni) {
            int col = colbase + (wc << 6) + (ni << 4) + r;
            float bv = bias[col];
            f32x4 v = acc[mi][ni];
            #pragma unroll
            for (int j = 0; j < 4; ++j)
                Cv[(size_t)(rw + j) * DM_ + col] = f2b(v[j] + bv);
        }
    }
}

// ---------------------------------------------------------------
// MFMA GEMM with optional fused RMSNorm row-scale (ASCALE).
template <int K, int N, bool CBF, bool ASCALE>
__global__ void __launch_bounds__(256) k_mgemm(const ushort_t* __restrict__ A, const int lda,
                                               const ushort_t* __restrict__ Wt,
                                               void* __restrict__ Cv, const int ldc, const int coff,
                                               const float* __restrict__ bias) {
    __shared__ ushort_t Al[128 * 64];
    __shared__ ushort_t Bl[128 * 64];
    const int tid = threadIdx.x;
    const int w = tid >> 6, lane = tid & 63;
    const int wr = w >> 1, wc = w & 1;
    const int rowbase = blockIdx.y * 128;
    const int colbase = blockIdx.x * 128;
    const int g = lane >> 4, r = lane & 15;

    f32x4 acc[4][4];
    #pragma unroll
    for (int i = 0; i < 4; ++i)
        #pragma unroll
        for (int j = 0; j < 4; ++j) acc[i][j] = (f32x4){0.f, 0.f, 0.f, 0.f};
    float rs[4] = {0.f, 0.f, 0.f, 0.f};

    for (int k0 = 0; k0 < K; k0 += 64) {
        __syncthreads();
        #pragma unroll
        for (int it = 0; it < 4; ++it) {
            int s = it * 256 + (w << 6) + lane;
            int row = s >> 3;
            int c16 = (s & 7) ^ (row & 7);
            gload_lds16(A + (size_t)(rowbase + row) * lda + k0 + c16 * 8,
                        &Al[(size_t)(it * 256 + (w << 6)) * 8]);
        }
        #pragma unroll
        for (int it = 0; it < 4; ++it) {
            int s = it * 256 + (w << 6) + lane;
            int row = s >> 3;
            int c16 = (s & 7) ^ (row & 7);
            gload_lds16(Wt + (size_t)(colbase + row) * K + k0 + c16 * 8,
                        &Bl[(size_t)(it * 256 + (w << 6)) * 8]);
        }
        __syncthreads();

        short8 af[2][4], bf[2][4];
        #pragma unroll
        for (int ks = 0; ks < 2; ++ks)
            #pragma unroll
            for (int mi = 0; mi < 4; ++mi) {
                int row = (wr << 6) + (mi << 4) + r;
                int c16 = ((ks << 2) | g) ^ (row & 7);
                af[ks][mi] = *(const short8*)&Al[(size_t)((row << 3) + c16) * 8];
            }
        #pragma unroll
        for (int ks = 0; ks < 2; ++ks)
            #pragma unroll
            for (int ni = 0; ni < 4; ++ni) {
                int row = (wc << 6) + (ni << 4) + r;
                int c16 = ((ks << 2) | g) ^ (row & 7);
                bf[ks][ni] = *(const short8*)&Bl[(size_t)((row << 3) + c16) * 8];
            }
        if (ASCALE) {
            #pragma unroll
            for (int ks = 0; ks < 2; ++ks)
                #pragma unroll
                for (int mi = 0; mi < 4; ++mi)
                    #pragma unroll
                    for (int e = 0; e < 8; ++e) {
                        float v = b2f((ushort_t)af[ks][mi][e]);
                        rs[mi] += v * v;
                    }
        }
        #pragma unroll
        for (int ks = 0; ks < 2; ++ks)
            #pragma unroll
            for (int mi = 0; mi < 4; ++mi)
                #pragma unroll
                for (int ni = 0; ni < 4; ++ni)
                    acc[mi][ni] = __builtin_amdgcn_mfma_f32_16x16x32_bf16(
                        af[ks][mi], bf[ks][ni], acc[mi][ni], 0, 0, 0);
    }

    #pragma unroll
    for (int mi = 0; mi < 4; ++mi) {
        int rw = rowbase + (wr << 6) + (mi << 4) + (g << 2);
        float sj[4] = {1.f, 1.f, 1.f, 1.f};
        if (ASCALE) {
            float s = rs[mi];
            s += __shfl_xor(s, 16);
            s += __shfl_xor(s, 32);
            float sc = rsqrtf(s * (1.f / 512.f) + 1e-5f);
            #pragma unroll
            for (int j = 0; j < 4; ++j) sj[j] = __shfl(sc, 4 * g + j);
        }
        #pragma unroll
        for (int ni = 0; ni < 4; ++ni) {
            int col = colbase + (wc << 6) + (ni << 4) + r;
            if (col < N) {
                float bv = bias ? bias[col] : 0.f;
                f32x4 v = acc[mi][ni];
                #pragma unroll
                for (int j = 0; j < 4; ++j) {
                    size_t cidx = (size_t)(rw + j) * ldc + coff + col;
                    float vr = v[j] * sj[j] + bv;
                    if (CBF) ((ushort_t*)Cv)[cidx] = f2b(vr);
                    else     ((float*)Cv)[cidx]   = vr;
                }
            }
        }
    }
}

// ---------------------------------------------------------------
// causal depthwise conv + silu; brec: B[0..15] C[16..31] dA[32..39] dt[40..47] ldA[48..55]
__global__ void __launch_bounds__(256) k_conv(const ushort_t* __restrict__ xbcdt,
                                              const float* __restrict__ cw,
                                              const float* __restrict__ cb,
                                              const float* __restrict__ dtb,
                                              const float* __restrict__ alog,
                                              ushort_t* __restrict__ xbc,
                                              float* __restrict__ brec) {
    int tid = threadIdx.x;
    int rb = blockIdx.x * 8;
    int srb = rb & (L_SEQ - 1);
    #pragma unroll
    for (int it = 0; it < 3; ++it) {
        int ch = it * 256 + tid;
        if (ch >= 552) break;
        if (ch < CONV_DIM_) {
            float w0 = cw[ch * 4 + 0], w1 = cw[ch * 4 + 1];
            float w2 = cw[ch * 4 + 2], w3 = cw[ch * 4 + 3];
            float bias = cb[ch];
            float win[11];
            #pragma unroll
            for (int j = 0; j < 11; ++j) {
                int sj = srb + j - 3;
                win[j] = (sj >= 0) ? b2f(xbcdt[(size_t)(rb + j - 3) * 640 + ch]) : 0.f;
            }
            #pragma unroll
            for (int r = 0; r < 8; ++r) {
                float acc = bias + win[r] * w0 + win[r + 1] * w1 + win[r + 2] * w2 + win[r + 3] * w3;
                float s = acc / (1.f + __expf(-acc));
                size_t row = rb + r;
                if (ch < 512) xbc[row * 512 + ch] = f2b(s);
                else          brec[row * RECW + (ch - 512)] = s;
            }
        } else {
            int h = ch - CONV_DIM_;
            float A = -__expf(alog[h]);
            float db = dtb[h];
            #pragma unroll
            for (int r = 0; r < 8; ++r) {
                size_t row = rb + r;
                float v = b2f(xbcdt[row * 640 + ch]) + db;
                float sp = (v > 20.f) ? v : log1pf(__expf(v));
                brec[row * RECW + 32 + h] = __expf(sp * A);   // dA
                brec[row * RECW + 40 + h] = sp;               // dt
                brec[row * RECW + 48 + h] = sp * A;           // ldA (log decay)
            }
        }
    }
}

// ---------------------------------------------------------------
// scan phase 1 via MFMA: chunk-final states + per-chunk decay.
// S_final[p][n] = sum_j Xh^T[p][j] * (B[j][n]*dt_j*exp(S63-S_j)); cdf = exp(S63).
// one wave per (b,h,c); grid (NCH, 8, B).
__global__ void __launch_bounds__(64) k_scan1m(const ushort_t* __restrict__ xbc,
                                               const float* __restrict__ brec,
                                               float* __restrict__ sbuf,
                                               float* __restrict__ cdf) {
    __shared__ ushort_t XhT[64 * 72];   // [p][j] bf16
    __shared__ float    Bst[64 * 20];   // staged B f32 [j][n], pad 20
    __shared__ ushort_t BwT[16 * 72];   // [n][j] bf16
    const int c = blockIdx.x, h = blockIdx.y, b = blockIdx.z;
    const int lane = threadIdx.x;
    const int g = lane >> 4, r = lane & 15;
    const size_t row0 = (size_t)b * L_SEQ + (size_t)c * QCH;

    // own row xh
    uint4 xw[8];
    {
        const uint4* xsrc = (const uint4*)(xbc + (row0 + lane) * 512 + h * 64);
        #pragma unroll
        for (int q = 0; q < 8; ++q) xw[q] = xsrc[q];
    }
    // stage B (cols 0..15) coalesced into LDS
    #pragma unroll
    for (int it2 = 0; it2 < 4; ++it2) {
        int idx = it2 * 64 + lane;           // 0..255
        int row = idx >> 2, q = idx & 3;
        float4 v = *(const float4*)(brec + (row0 + row) * RECW + q * 4);
        *(float4*)&Bst[row * 20 + q * 4] = v;
    }
    float ldA = brec[(row0 + lane) * RECW + 48 + h];
    float dtv = brec[(row0 + lane) * RECW + 40 + h];

    // Kogge-Stone inclusive prefix of ldA
    float S = ldA;
    #pragma unroll
    for (int d = 1; d < 64; d <<= 1) {
        float o = __shfl(S, (lane >= d) ? (lane - d) : 0);
        if (lane >= d) S += o;
    }
    float Stot = __shfl(S, 63);
    float wj = dtv * __expf(Stot - S);       // Stot - S <= 0: safe

    // transpose xh row into XhT[p][lane]
    #pragma unroll
    for (int p = 0; p < 64; ++p) {
        uint4 v = xw[p >> 3];
        int sub = (p >> 1) & 3;
        uint_t word = (sub == 0) ? v.x : (sub == 1) ? v.y : (sub == 2) ? v.z : v.w;
        XhT[p * 72 + lane] = (ushort_t)((p & 1) ? (word >> 16) : (word & 0xffffu));
    }
    __syncthreads();

    // BwT[n][lane] = bf16( B[lane][n] * wj )
    {
        const float* bp = &Bst[lane * 20];
        float4 b0 = *(const float4*)bp;
        float4 b1 = *(const float4*)(bp + 4);
        float4 b2 = *(const float4*)(bp + 8);
        float4 b3 = *(const float4*)(bp + 12);
        float bv[16] = {b0.x,b0.y,b0.z,b0.w, b1.x,b1.y,b1.z,b1.w,
                        b2.x,b2.y,b2.z,b2.w, b3.x,b3.y,b3.z,b3.w};
        #pragma unroll
        for (int n = 0; n < 16; ++n)
            BwT[n * 72 + lane] = f2b(bv[n] * wj);
    }
    __syncthreads();

    short8 bwtf[2];
    bwtf[0] = *(const short8*)&BwT[r * 72 + 0  + g * 8];
    bwtf[1] = *(const short8*)&BwT[r * 72 + 32 + g * 8];

    size_t base = ((size_t)(b * 8 + h) * NCH + c) * 1024;
    #pragma unroll
    for (int p0t = 0; p0t < 4; ++p0t) {
        short8 a0 = *(const short8*)&XhT[(p0t * 16 + r) * 72 + 0  + g * 8];
        short8 a1 = *(const short8*)&XhT[(p0t * 16 + r) * 72 + 32 + g * 8];
        f32x4 acc = (f32x4){0.f, 0.f, 0.f, 0.f};
        acc = __builtin_amdgcn_mfma_f32_16x16x32_bf16(a0, bwtf[0], acc, 0, 0, 0);
        acc = __builtin_amdgcn_mfma_f32_16x16x32_bf16(a1, bwtf[1], acc, 0, 0, 0);
        // D: col=r -> n, row=g*4+reg -> p (within tile)
        #pragma unroll
        for (int reg = 0; reg < 4; ++reg)
            sbuf[base + (size_t)(p0t * 16 + g * 4 + reg) * 16 + r] = acc[reg];
    }
    if (lane == 63) cdf[(b * 8 + h) * NCH + c] = __expf(S);   // S@63 = Stot
}

// ---------------------------------------------------------------
// phase 2: sequential chain over chunks (tiny).
__global__ void __launch_bounds__(256) k_chain(const float* __restrict__ sbuf,
                                               const float* __restrict__ cdf,
                                               float* __restrict__ hin) {
    int h = blockIdx.x, b = blockIdx.y;
    int tid = threadIdx.x;
    float4 H = make_float4(0.f, 0.f, 0.f, 0.f);
    size_t base = (size_t)((b * 8 + h) * NCH) * 1024;
    for (int c = 0; c < NCH; ++c) {
        *(float4*)&hin[base + (size_t)c * 1024 + tid * 4] = H;
        float cdfv = cdf[(b * 8 + h) * NCH + c];
        float4 S = *(const float4*)&sbuf[base + (size_t)c * 1024 + tid * 4];
        H.x = cdfv * H.x + S.x;
        H.y = cdfv * H.y + S.y;
        H.z = cdfv * H.z + S.z;
        H.w = cdfv * H.w + S.w;
    }
}

// ---------------------------------------------------------------
// SSD scan phase 3 via MFMA: per (b,h,c) one wave.
// Y = P @ Xh + diag(exp S)·(C @ Hin), P[i][j] = (C_i·B_j)·exp(S_i-S_j)·dt_j (j<=i).
// B/C staged coalesced as bf16 (recBC overlays Pl). Then y += D*xh, gate, write yg.
__global__ void __launch_bounds__(64) k_ssc2(const ushort_t* __restrict__ xbc,
                                             const ushort_t* __restrict__ z_bf,
                                             const float* __restrict__ brec,
                                             const float* __restrict__ Dp,
                                             const float* __restrict__ hin,
                                             ushort_t* __restrict__ yg_out) {
    __shared__ ushort_t XhT[64 * 72];   // [p][j] bf16
    __shared__ ushort_t Pl [64 * 72];   // first: recBC [64][40] bf16 (B 0..15, C 16..31); then P [i][j]
    __shared__ float Sl[64], Tl[64], El[64];
    const int c = blockIdx.x, h = blockIdx.y, b = blockIdx.z;
    const int lane = threadIdx.x;
    const int g = lane >> 4, r = lane & 15;
    const size_t row0 = (size_t)b * L_SEQ + (size_t)c * QCH;
    const size_t bhc = (size_t)(b * 8 + h) * NCH + c;

    // own row xh
    uint4 xw[8];
    {
        const uint4* xsrc = (const uint4*)(xbc + (row0 + lane) * 512 + h * 64);
        #pragma unroll
        for (int q = 0; q < 8; ++q) xw[q] = xsrc[q];
    }
    // stage B+C (cols 0..31) coalesced -> bf16 recBC (in Pl buffer, stride 40)
    #pragma unroll
    for (int it2 = 0; it2 < 8; ++it2) {
        int idx = it2 * 64 + lane;           // 0..511
        int row = idx >> 3, q = idx & 7;
        float4 v = *(const float4*)(brec + (row0 + row) * RECW + q * 4);
        uint_t u0 = (uint_t)f2b(v.x) | ((uint_t)f2b(v.y) << 16);
        uint_t u1 = (uint_t)f2b(v.z) | ((uint_t)f2b(v.w) << 16);
        *(uint2*)&Pl[row * 40 + q * 4] = make_uint2(u0, u1);
    }
    float ldA = brec[(row0 + lane) * RECW + 48 + h];
    float dtv = brec[(row0 + lane) * RECW + 40 + h];

    // Kogge-Stone inclusive prefix of ldA
    float S = ldA;
    #pragma unroll
    for (int d = 1; d < 64; d <<= 1) {
        float o = __shfl(S, (lane >= d) ? (lane - d) : 0);
        if (lane >= d) S += o;
    }
    Sl[lane] = S;
    Tl[lane] = S - __logf(dtv);
    El[lane] = __expf(S);

    // transpose xh row into XhT[p][lane]
    #pragma unroll
    for (int p = 0; p < 64; ++p) {
        uint4 v = xw[p >> 3];
        int sub = (p >> 1) & 3;
        uint_t word = (sub == 0) ? v.x : (sub == 1) ? v.y : (sub == 2) ? v.z : v.w;
        XhT[p * 72 + lane] = (ushort_t)((p & 1) ? (word >> 16) : (word & 0xffffu));
    }
    __syncthreads();

    // C/B fragments from staged recBC, K padded 16->32 (g>=2 zero)
    short8 cwf[4], bwf[4];
    #pragma unroll
    for (int t4 = 0; t4 < 4; ++t4) {
        if (g < 2) {
            bwf[t4] = *(const short8*)&Pl[(t4 * 16 + r) * 40 + 0  + g * 8];
            cwf[t4] = *(const short8*)&Pl[(t4 * 16 + r) * 40 + 16 + g * 8];
        } else {
            #pragma unroll
            for (int e = 0; e < 8; ++e) { bwf[t4][e] = 0; cwf[t4][e] = 0; }
        }
    }
    __syncthreads();

    // ---- MFMA-1: M^T[j][i] = sum_n B[j][n] C[i][n]; mask -> P (bf16, overwrites recBC)
    #pragma unroll
    for (int j0t = 0; j0t < 4; ++j0t) {
        #pragma unroll
        for (int i0t = 0; i0t < 4; ++i0t) {
            f32x4 m = (f32x4){0.f, 0.f, 0.f, 0.f};
            m = __builtin_amdgcn_mfma_f32_16x16x32_bf16(bwf[j0t], cwf[i0t], m, 0, 0, 0);
            // D: col=lane&15 -> i, row=g*4+reg -> j
            int i = i0t * 16 + r;
            float si = Sl[i];
            float4 tj = *(const float4*)&Tl[j0t * 16 + g * 4];
            ushort_t pv[4];
            #pragma unroll
            for (int reg = 0; reg < 4; ++reg) {
                int j = j0t * 16 + g * 4 + reg;
                float tjv = (reg == 0) ? tj.x : (reg == 1) ? tj.y : (reg == 2) ? tj.z : tj.w;
                float mask = (j <= i) ? __expf(si - tjv) : 0.f;
                pv[reg] = f2b(m[reg] * mask);
            }
            uint2 packed = make_uint2((uint_t)pv[0] | ((uint_t)pv[1] << 16),
                                      (uint_t)pv[2] | ((uint_t)pv[3] << 16));
            *(uint2*)&Pl[i * 72 + j0t * 16 + g * 4] = packed;
        }
    }
    __syncthreads();

    // ---- hoist Xh B-frags and Hin boundary B-frags
    short8 xhf[4][2];
    #pragma unroll
    for (int p0t = 0; p0t < 4; ++p0t)
        #pragma unroll
        for (int kk = 0; kk < 2; ++kk)
            xhf[p0t][kk] = *(const short8*)&XhT[(p0t * 16 + r) * 72 + kk * 32 + g * 8];
    short8 hinf[4];
    #pragma unroll
    for (int p0t = 0; p0t < 4; ++p0t)
        hinf[p0t] = frag8(hin + bhc * 1024 + (size_t)(p0t * 16 + r) * 16 + g * 8, g < 2);

    const float Dh = Dp[h];

    // ---- per output tile: boundary MFMA, scale by exp(S_i), P@Xh, epilogue
    #pragma unroll
    for (int i0t = 0; i0t < 4; ++i0t) {
        short8 pa0 = *(const short8*)&Pl[(i0t * 16 + r) * 72 + 0  + g * 8];
        short8 pa1 = *(const short8*)&Pl[(i0t * 16 + r) * 72 + 32 + g * 8];
        float4 e4 = *(const float4*)&El[i0t * 16 + g * 4];
        #pragma unroll
        for (int p0t = 0; p0t < 4; ++p0t) {
            f32x4 acc = (f32x4){0.f, 0.f, 0.f, 0.f};
            acc = __builtin_amdgcn_mfma_f32_16x16x32_bf16(cwf[i0t], hinf[p0t], acc, 0, 0, 0);
            acc[0] *= e4.x; acc[1] *= e4.y; acc[2] *= e4.z; acc[3] *= e4.w;
            acc = __builtin_amdgcn_mfma_f32_16x16x32_bf16(pa0, xhf[p0t][0], acc, 0, 0, 0);
            acc = __builtin_amdgcn_mfma_f32_16x16x32_bf16(pa1, xhf[p0t][1], acc, 0, 0, 0);
            int p = p0t * 16 + r;
            #pragma unroll
            for (int reg = 0; reg < 4; ++reg) {
                int i = i0t * 16 + g * 4 + reg;
                size_t row = row0 + i;
                float xhv = b2f(XhT[p * 72 + i]);
                float y = acc[reg] + Dh * xhv;
                float zz = b2f(z_bf[row * 512 + h * 64 + p]);
                float ygv = y * (zz / (1.f + __expf(-zz)));
                yg_out[row * 512 + h * 64 + p] = f2b(ygv);
            }
        }
    }
}

// ---------------------------------------------------------------
__global__ void __launch_bounds__(256) k_scatter(const ushort_t* __restrict__ tmp,
                                                 const float* __restrict__ ub,
                                                 const float* __restrict__ xin,
                                                 float* __restrict__ out) {
    int tid = threadIdx.x;
    int w = tid & 127;
    int h = (blockIdx.x << 1) | (tid >> 7);
    int c = blockIdx.y >> 3, t = blockIdx.y & 7;
    int b = blockIdx.z;
    size_t row = (size_t)b * L_SEQ + t * 1024 + (h >> 2) * 32 + (w >> 2);
    int kk = c * 16 + (h & 3) * 4 + (w & 3);
    size_t oidx = (((size_t)(b * C_INCH + c) * T_N + t) << 14) + (size_t)h * W_IMG + w;
    out[oidx] = b2f(tmp[row * KPATCH + kk]) + ub[c] + xin[oidx];
}

// ---------------------------------------------------------------
extern "C" void kernel_launch(void* const* d_in, const int* in_sizes, int n_in,
                              void* d_out, int out_size, void* d_ws, size_t ws_size,
                              hipStream_t stream) {
    const float* x       = (const float*)d_in[0];
    const float* patch_w = (const float*)d_in[1];
    const float* patch_b = (const float*)d_in[2];
    const float* W_in    = (const float*)d_in[3];
    const float* conv_w  = (const float*)d_in[4];
    const float* conv_b  = (const float*)d_in[5];
    const float* dt_bias = (const float*)d_in[6];
    const float* A_log   = (const float*)d_in[7];
    const float* D_param = (const float*)d_in[8];
    const float* norm_w  = (const float*)d_in[9];
    const float* W_out   = (const float*)d_in[10];
    const float* unemb_w = (const float*)d_in[11];
    const float* unemb_b = (const float*)d_in[12];
    float* out = (float*)d_out;

    // ---- workspace carve ----
    char* p = (char*)d_ws;
    ushort_t* scratch = (ushort_t*)p; p += (size_t)BLROWS * 384 * 2;   // 25 MB (bf16 tmp)
    float* cdf  = (float*)p;   p += (size_t)32 * NCH * 4;
    float* sbuf = (float*)p;   p += (size_t)32 * NCH * 1024 * 4;       // 16.8 MB
    float* hin  = (float*)p;   p += (size_t)32 * NCH * 1024 * 4;       // 16.8 MB
    float* brec = (float*)p;   p += (size_t)BLROWS * RECW * 4;         // 7.3 MB
    ushort_t* Wt_p   = (ushort_t*)p; p += (size_t)256 * 384 * 2;
    ushort_t* Wt_in  = (ushort_t*)p; p += (size_t)1152 * 256 * 2;
    ushort_t* Wt_out = (ushort_t*)p; p += (size_t)256 * 512 * 2;
    ushort_t* Wt_un  = (ushort_t*)p; p += (size_t)384 * 256 * 2;
    ushort_t* xs     = (ushort_t*)p; p += (size_t)BLROWS * DM_ * 2;    // 16.8 MB
    ushort_t* xbc    = (ushort_t*)p; p += (size_t)BLROWS * 512 * 2;    // 33.5 MB
    ushort_t* z_bf   = (ushort_t*)p; p += (size_t)BLROWS * 512 * 2;    // 33.5 MB
    ushort_t* xbcdt  = (ushort_t*)p; p += (size_t)BLROWS * 640 * 2;    // 41.9 MB (later: yg)
    size_t need = (size_t)(p - (char*)d_ws);
    if (ws_size < need) return;

    ushort_t* tmp = scratch;            // bf16 unembed output
    ushort_t* yg  = xbcdt;              // yg overlays xbcdt (dead after conv)

    k_castpad<<<256, 384, 0, stream>>>(patch_w, Wt_p);
    k_transcast<<<1152, 256, 0, stream>>>(W_in, Wt_in, 256, 1064, nullptr);
    k_transcast<<<256, 256, 0, stream>>>(W_out, Wt_out, 512, 256, norm_w);  // fold RMSNorm weight
    k_transcast<<<384, 256, 0, stream>>>(unemb_w, Wt_un, 256, 368, nullptr);

    // fused im2col + patch GEMM
    k_pgemm<<<dim3(2, 256), 256, 0, stream>>>(x, Wt_p, xs, patch_b);

    // in-proj split: z cols 0..511 -> z_bf; xBC+dt cols 512..1063 -> xbcdt
    k_mgemm<256, 512, true, false><<<dim3(4, 256), 256, 0, stream>>>(xs, 256, Wt_in, z_bf, 512, 0, nullptr);
    k_mgemm<256, 552, true, false><<<dim3(5, 256), 256, 0, stream>>>(xs, 256, Wt_in + (size_t)512 * 256, xbcdt, 640, 0, nullptr);

    k_conv<<<BLROWS / 8, 256, 0, stream>>>(xbcdt, conv_w, conv_b, dt_bias, A_log, xbc, brec);

    k_scan1m<<<dim3(NCH, 8, 4), 64, 0, stream>>>(xbc, brec, sbuf, cdf);
    k_chain<<<dim3(8, 4), 256, 0, stream>>>(sbuf, cdf, hin);
    k_ssc2<<<dim3(NCH, 8, 4), 64, 0, stream>>>(xbc, z_bf, brec, D_param, hin, yg);

    // out-proj with in-kernel fused RMSNorm (ASCALE): out_seq bf16 -> xs
    k_mgemm<512, 256, true, true><<<dim3(2, 256), 256, 0, stream>>>(yg, 512, Wt_out, xs, DM_, 0, nullptr);

    k_mgemm<256, 368, true, false><<<dim3(3, 256), 256, 0, stream>>>(xs, 256, Wt_un, tmp, KPATCH, 0, nullptr);

    k_scatter<<<dim3(64, 184, 4), 256, 0, stream>>>(tmp, unemb_b, x, out);
}